// Round 13
// baseline (759.301 us; speedup 1.0000x reference)
//
#include <hip/hip_runtime.h>
#include <cstdint>

// ---------------------------------------------------------------------------
// DDPM + VAE query encoder, MI355X round 25.
// r24 post-mortem: chain-ILP split was NEUTRAL -> intra-segment latency is
// not the gate. Model: step = skeleton 3190 cy (r19 chunk) + ~1900 cy of
// noise that fails to PACK into skeleton idle at 16 waves/CU (512x512 grid
// = 2 blocks/CU; 512-thr WGs cap at 4/CU). r25: reach the 32-waves/CU
// thread cap with SMALL blocks: 2048 blocks x 256 thr (4 waves, 4 rows).
//  - Each wave: full-K GEMV for its 16-col group; A-rows 4-15 are zeroed
//    padding (garbage C rows never stored; MFMA 8%-util -> 4x chip MFMA is
//    ~1536 cy/step/SIMD matrix-pipe, affordable).
//  - All waves: 1 noise draw/lane/step (r24 bits/erfinv split kept).
//  - waves_per_eu(4,8): min 4 = 128-VGPR no-spill budget (need ~52),
//    max 8 = full residency allowed. LDS 11.4 KB x 8 blocks = 91 KB/CU.
// Same threefry bits -> absmax unchanged.
// ---------------------------------------------------------------------------

#define DEVI __device__ __forceinline__

typedef __attribute__((ext_vector_type(8))) short short8;
typedef __attribute__((ext_vector_type(4))) float f32x4;

DEVI void threefry2x32(uint32_t k0, uint32_t k1, uint32_t x0, uint32_t x1,
                       uint32_t &o0, uint32_t &o1)
{
  const uint32_t ks2 = k0 ^ k1 ^ 0x1BD11BDAu;
  x0 += k0; x1 += k1;
#define TFR(r) { x0 += x1; x1 = __builtin_rotateleft32(x1, r); x1 ^= x0; }
  TFR(13u) TFR(15u) TFR(26u) TFR(6u)   x0 += k1;  x1 += ks2 + 1u;
  TFR(17u) TFR(29u) TFR(16u) TFR(24u)  x0 += ks2; x1 += k0 + 2u;
  TFR(13u) TFR(15u) TFR(26u) TFR(6u)   x0 += k0;  x1 += k1 + 3u;
  TFR(17u) TFR(29u) TFR(16u) TFR(24u)  x0 += k1;  x1 += ks2 + 4u;
  TFR(13u) TFR(15u) TFR(26u) TFR(6u)   x0 += ks2; x1 += k0 + 5u;
#undef TFR
  o0 = x0; o1 = x1;
}

DEVI uint32_t jax_random_bits32(uint32_t k0, uint32_t k1, uint32_t j)
{
  uint32_t a, b;
  threefry2x32(k0, k1, 0u, j, a, b);
  return a ^ b;
}

DEVI float jax_bits_to_normal(uint32_t bits)
{
  const float LO = -0.99999994f;
  float f = __uint_as_float((bits >> 9) | 0x3f800000u) - 1.0f;
  float u = fmaxf(LO, f * 2.0f + LO);
  float w = -__logf((1.0f - u) * (1.0f + u));
  float p;
  if (w < 5.0f) {
    w = w - 2.5f;
    p =              2.81022636e-08f;
    p = fmaf(p, w,   3.43273939e-07f);
    p = fmaf(p, w,  -3.5233877e-06f);
    p = fmaf(p, w,  -4.39150654e-06f);
    p = fmaf(p, w,   0.00021858087f);
    p = fmaf(p, w,  -0.00125372503f);
    p = fmaf(p, w,  -0.00417768164f);
    p = fmaf(p, w,   0.246640727f);
    p = fmaf(p, w,   1.50140941f);
  } else {
    w = sqrtf(w) - 3.0f;
    p =             -0.000200214257f;
    p = fmaf(p, w,   0.000100950558f);
    p = fmaf(p, w,   0.00134934322f);
    p = fmaf(p, w,  -0.00367342844f);
    p = fmaf(p, w,   0.00573950773f);
    p = fmaf(p, w,  -0.0076224613f);
    p = fmaf(p, w,   0.00943887047f);
    p = fmaf(p, w,   1.00167406f);
    p = fmaf(p, w,   2.83297682f);
  }
  return 1.41421356237f * (p * u);
}

DEVI short bf16_hi_trunc(float x) { return (short)(__float_as_uint(x) >> 16); }
DEVI float bf16_to_f32(short h)
{
  return __uint_as_float(((uint32_t)(unsigned short)h) << 16);
}
DEVI void split_bf16(float x, short &h, short &l)
{
  h = bf16_hi_trunc(x);
  float r = x - bf16_to_f32(h);
  l = bf16_hi_trunc(r);
}

// 8-short fragment from 16B-aligned LDS (stride-72 rows): one b128 read.
DEVI short8 ld_frag16(const short* p)
{
  union { int4 v; short8 s; } u;
  u.v = *(const int4*)p;
  return u.s;
}

// ---------------------------------------------------------------------------
// k_poolprep: blocks [0,2048) = pool (4 rows each); blocks [2048,2248) =
// prep for t = blockIdx-2048. Independent inputs; prep hides under pool.
__global__ __launch_bounds__(256)
void k_poolprep(const int* __restrict__ seq, const float* __restrict__ emb,
                float* __restrict__ pooled,
                const float* __restrict__ Wt, const float* __restrict__ bt,
                const float* __restrict__ bin, float* __restrict__ tpb,
                float* __restrict__ sched)
{
  if (blockIdx.x < 2048u) {
    const int lane = threadIdx.x & 63;
    const int r    = blockIdx.x * 4 + (threadIdx.x >> 6);
    const int* row = seq + r * 100;
    float s = 0.f;
    int cnt = 0;
    for (int l = 0; l < 100; ++l) {
      int id = row[l];
      cnt += (id != 0);
      s += emb[id * 64 + lane];
    }
    pooled[r * 64 + lane] = s / sqrtf((float)cnt);
  } else {
    __shared__ float temb[64];
    const int t = blockIdx.x - 2048;
    const int d = threadIdx.x;
    if (d < 64) {
      const float lg = logf(10000.0f);
      int i = d & 31;
      float fr  = expf((-lg * (float)i) / 32.0f);
      float ang = (float)t * fr;
      temb[d] = (d < 32) ? cosf(ang) : sinf(ang);
      if (d == 0) {
        const float start = (float)(5.0 * 1e-4);
        const float stop  = (float)(5.0 * 0.02);
        const float delta = stop - start;
        float prod = 1.f, acp_prev = 1.f, beta = 0.f, alpha = 1.f;
        for (int i2 = 0; i2 <= t; ++i2) {
          beta  = start + ((float)i2 * delta) / 199.0f;
          alpha = 1.0f - beta;
          acp_prev = prod;
          prod = prod * alpha;
        }
        float acp = prod;
        float om  = 1.0f - acp;
        sched[t * 8 + 0] = sqrtf(1.0f / acp);
        sched[t * 8 + 1] = sqrtf(1.0f / acp - 1.0f);
        sched[t * 8 + 2] = beta * sqrtf(acp_prev) / om;
        sched[t * 8 + 3] = (1.0f - acp_prev) * sqrtf(alpha) / om;
        float pv = beta * (1.0f - acp_prev) / om;
        sched[t * 8 + 4] = (t > 0) ? sqrtf(pv) : 0.0f;
        uint32_t fk0, fk1;
        threefry2x32(0u, 2u, 0u, (uint32_t)t, fk0, fk1);
        ((uint32_t*)sched)[t * 8 + 5] = fk0;
        ((uint32_t*)sched)[t * 8 + 6] = fk1;
      }
    }
    __syncthreads();
    if (d < 64) {
      float acc = bt[d] + bin[d];
      for (int k = 0; k < 64; ++k)
        acc = fmaf(temb[k], Wt[k * 64 + d], acc);
      tpb[t * 64 + d] = acc;
    }
  }
}

// ---------------------------------------------------------------------------
__global__ __launch_bounds__(256)
void k_enc(const float* __restrict__ pooled,
           const float* __restrict__ W1, const float* __restrict__ b1,
           const float* __restrict__ W2, const float* __restrict__ b2,
           const float* __restrict__ Wc, const float* __restrict__ bc,
           float* __restrict__ cproj)
{
  __shared__ float p_s[8][64];
  __shared__ float h_s[8][256];
  __shared__ float mu_s[8][64];
  const int tid = threadIdx.x;
  const int r0  = blockIdx.x * 8;

  for (int i = tid; i < 8 * 64; i += 256)
    p_s[i >> 6][i & 63] = pooled[r0 * 64 + i];
  __syncthreads();

  float hacc[8];
#pragma unroll
  for (int r = 0; r < 8; ++r) hacc[r] = b1[tid];
  for (int k = 0; k < 64; ++k) {
    float w = W1[k * 256 + tid];
#pragma unroll
    for (int r = 0; r < 8; ++r) hacc[r] = fmaf(p_s[r][k], w, hacc[r]);
  }
#pragma unroll
  for (int r = 0; r < 8; ++r) h_s[r][tid] = fmaxf(hacc[r], 0.f);
  __syncthreads();

#pragma unroll
  for (int pass = 0; pass < 2; ++pass) {
    int r = pass * 4 + (tid >> 6);
    int j = tid & 63;
    float acc = b2[j];
    for (int k = 0; k < 256; ++k)
      acc = fmaf(h_s[r][k], W2[k * 128 + j], acc);
    mu_s[r][j] = acc;
  }
  __syncthreads();

#pragma unroll
  for (int pass = 0; pass < 2; ++pass) {
    int r = pass * 4 + (tid >> 6);
    int j = tid & 63;
    float acc = bc[j];
    for (int k = 0; k < 64; ++k)
      acc = fmaf(mu_s[r][k], Wc[k * 64 + j], acc);
    cproj[(r0 + r) * 64 + j] = acc;
  }
}

// ---------------------------------------------------------------------------
// K_ddpm: 2048 blocks x 256 threads (4 waves). Block owns 4 rows.
// Wave w = col group (cols 16w..16w+15). A-rows 4-15 are zeroed padding;
// only quad 0 lanes own C rows 0-3 (quads 1-3 compute garbage, not stored).
// ALL lanes: 1 noise draw/step (bits in segA, erfinv+write in segB),
// producer cell cb = w*64+lane (bijective over the block's 256 cells).
#define XLDW  72   // X/H row stride (shorts); 144 B -> 16B-aligned frags
#define NBW   68   // nbuf row stride (floats)

__global__
__attribute__((amdgpu_flat_work_group_size(256, 256), amdgpu_waves_per_eu(4, 8)))
void k_ddpm(const float* __restrict__ Win, const float* __restrict__ Wout,
            const float* __restrict__ bout,
            const float* __restrict__ cproj, const float* __restrict__ tpb,
            const float* __restrict__ sched, float* __restrict__ out)
{
  __shared__ __align__(16) short Xh[16 * XLDW], Xl[16 * XLDW];
  __shared__ __align__(16) short Hh[16 * XLDW], Hl[16 * XLDW];
  __shared__ __align__(16) float nbuf[2 * 4 * NBW];
  // total: 4*2304 + 2176 = 11392 B -> 8 blocks/CU = 91 KB < 160 KB

  const int tid  = threadIdx.x;
  const int lane = tid & 63;
  const int w    = tid >> 6;                       // 0..3 = col group
  const int r0g  = blockIdx.x * 4;
  const uint32_t* su = (const uint32_t*)sched;

  const int nn   = lane & 15;
  const int quad = lane >> 4;
  const int dim  = w * 16 + nn;
  const int arow = nn;
  const int kq0  = quad * 8;
  const int kq1  = 32 + quad * 8;
  const bool own = (quad == 0);                    // C rows 0-3 only

  // ---- producer ids: 1 cell per lane
  const int cb   = w * 64 + lane;                  // 0..255 (row*64+dim)
  const uint32_t jn = (uint32_t)(r0g * 64 + cb);
  const int nrow = cb >> 6;
  const int ndim = cb & 63;
  float* nb_w = &nbuf[nrow * NBW + ndim];          // + buf*4*NBW at use

  // ---- zero all X/H rows (rows 4-15 stay zero forever: NaN-free padding)
  for (int i = tid; i < 16 * XLDW; i += 256) {
    Xh[i] = 0; Xl[i] = 0; Hh[i] = 0; Hl[i] = 0;
  }

  // ---- weight B-fragments -> registers
  short8 wiH0, wiL0, wiH1, wiL1, woH0, woL0, woH1, woL1;
#pragma unroll
  for (int j = 0; j < 8; ++j) {
    short h, l;
    split_bf16(Win[(kq0 + j) * 64 + dim], h, l);  wiH0[j] = h; wiL0[j] = l;
    split_bf16(Win[(kq1 + j) * 64 + dim], h, l);  wiH1[j] = h; wiL1[j] = l;
    split_bf16(Wout[(kq0 + j) * 64 + dim], h, l); woH0[j] = h; woL0[j] = l;
    split_bf16(Wout[(kq1 + j) * 64 + dim], h, l); woH1[j] = h; woL1[j] = l;
  }

  const float bo = bout[dim];
  const uint32_t j0 = (uint32_t)(r0g * 64 + dim);  // row 0 of block at dim
  float cp[4] = {0.f, 0.f, 0.f, 0.f}, xo[4] = {0.f, 0.f, 0.f, 0.f};

  if (own) {
#pragma unroll
    for (int r = 0; r < 4; ++r) cp[r] = cproj[j0 + r * 64u];
#pragma unroll
    for (int r = 0; r < 4; ++r) {
      xo[r] = jax_bits_to_normal(jax_random_bits32(0u, 1u, j0 + r * 64u));
      short h, l;
      split_bf16(xo[r], h, l);
      Xh[r * XLDW + dim] = h; Xl[r * XLDW + dim] = l;
    }
  }
  float tp = tpb[199 * 64 + dim];

  // prologue noise for t=199 into nbuf[1]: all 256 threads, 1 cell each
  {
    const uint32_t fk0 = su[199 * 8 + 5];
    const uint32_t fk1 = su[199 * 8 + 6];
    nb_w[4 * NBW] = jax_bits_to_normal(jax_random_bits32(fk0, fk1, jn));
  }
  __syncthreads();

#pragma unroll 1
  for (int t = 199; t >= 0; --t) {
    uint32_t gk0 = 0, gk1 = 0;
    float* nd = nullptr;
    if (t > 0) {
      gk0 = su[(t - 1) * 8 + 5];
      gk1 = su[(t - 1) * 8 + 6];
      nd = nb_w + ((t - 1) & 1) * 4 * NBW;
    }

    const float sr   = sched[t * 8 + 0];
    const float srm1 = sched[t * 8 + 1];
    const float c1   = sched[t * 8 + 2];
    const float c2   = sched[t * 8 + 3];
    const float sg   = sched[t * 8 + 4];

    // ---- phase A: in-GEMV, full K=64 (rows 4-15 of A are zeros)
    f32x4 acc;
#pragma unroll
    for (int r = 0; r < 4; ++r) acc[r] = tp + cp[r];
    {
      short8 xh0 = ld_frag16(&Xh[arow * XLDW + kq0]);
      short8 xl0 = ld_frag16(&Xl[arow * XLDW + kq0]);
      short8 xh1 = ld_frag16(&Xh[arow * XLDW + kq1]);
      short8 xl1 = ld_frag16(&Xl[arow * XLDW + kq1]);
      acc = __builtin_amdgcn_mfma_f32_16x16x32_bf16(xl0, wiH0, acc, 0, 0, 0);
      acc = __builtin_amdgcn_mfma_f32_16x16x32_bf16(xh0, wiL0, acc, 0, 0, 0);
      acc = __builtin_amdgcn_mfma_f32_16x16x32_bf16(xh0, wiH0, acc, 0, 0, 0);
      acc = __builtin_amdgcn_mfma_f32_16x16x32_bf16(xl1, wiH1, acc, 0, 0, 0);
      acc = __builtin_amdgcn_mfma_f32_16x16x32_bf16(xh1, wiL1, acc, 0, 0, 0);
      acc = __builtin_amdgcn_mfma_f32_16x16x32_bf16(xh1, wiH1, acc, 0, 0, 0);
    }
    if (own) {
#pragma unroll
      for (int r = 0; r < 4; ++r) {
        float v = acc[r];
        v = v * __builtin_amdgcn_rcpf(1.0f + __expf(-v));
        short h, l;
        split_bf16(v, h, l);
        Hh[r * XLDW + dim] = h; Hl[r * XLDW + dim] = l;
      }
    }
    int tn = (t > 0) ? (t - 1) : 0;
    float tpn = tpb[tn * 64 + dim];                // prefetch next tp

    // segA (all lanes): threefry bits for step t-1 (erfinv deferred)
    uint32_t b0 = 0;
    if (t > 0) b0 = jax_random_bits32(gk0, gk1, jn);
    __syncthreads();                                // B1

    {
      // noise for this step (buf t&1 fully written by end of iter t+1)
      float n[4];
#pragma unroll
      for (int r = 0; r < 4; ++r)
        n[r] = nbuf[(t & 1) * 4 * NBW + r * NBW + dim];

      // ---- phase B: out-GEMV, full K=64 (H rows 4-15 zeros)
      f32x4 eac;
#pragma unroll
      for (int r = 0; r < 4; ++r) eac[r] = bo;
      {
        short8 hh0 = ld_frag16(&Hh[arow * XLDW + kq0]);
        short8 hl0 = ld_frag16(&Hl[arow * XLDW + kq0]);
        short8 hh1 = ld_frag16(&Hh[arow * XLDW + kq1]);
        short8 hl1 = ld_frag16(&Hl[arow * XLDW + kq1]);
        eac = __builtin_amdgcn_mfma_f32_16x16x32_bf16(hl0, woH0, eac, 0, 0, 0);
        eac = __builtin_amdgcn_mfma_f32_16x16x32_bf16(hh0, woL0, eac, 0, 0, 0);
        eac = __builtin_amdgcn_mfma_f32_16x16x32_bf16(hh0, woH0, eac, 0, 0, 0);
        eac = __builtin_amdgcn_mfma_f32_16x16x32_bf16(hl1, woH1, eac, 0, 0, 0);
        eac = __builtin_amdgcn_mfma_f32_16x16x32_bf16(hh1, woL1, eac, 0, 0, 0);
        eac = __builtin_amdgcn_mfma_f32_16x16x32_bf16(hh1, woH1, eac, 0, 0, 0);
      }
      if (own) {
#pragma unroll
        for (int r = 0; r < 4; ++r) {
          float xc = fminf(1.f, fmaxf(-1.f, sr * xo[r] - srm1 * eac[r]));
          xo[r] = c1 * xc + c2 * xo[r] + sg * n[r];
          short h, l;
          split_bf16(xo[r], h, l);
          Xh[r * XLDW + dim] = h; Xl[r * XLDW + dim] = l;
        }
      }
      tp = tpn;
    }
    // segB (all lanes): erfinv + nbuf write for step t-1
    if (t > 0) nd[0] = jax_bits_to_normal(b0);
    __syncthreads();                                // B2
  }

  if (own) {
#pragma unroll
    for (int r = 0; r < 4; ++r) out[j0 + r * 64u] = xo[r];
  }
}

// ---------------------------------------------------------------------------
extern "C" void kernel_launch(void* const* d_in, const int* in_sizes, int n_in,
                              void* d_out, int out_size, void* d_ws, size_t ws_size,
                              hipStream_t stream)
{
  const int*   seq  = (const int*)  d_in[0];
  const float* emb  = (const float*)d_in[1];
  const float* W1   = (const float*)d_in[2];
  const float* b1   = (const float*)d_in[3];
  const float* W2   = (const float*)d_in[4];
  const float* b2   = (const float*)d_in[5];
  const float* Win  = (const float*)d_in[6];
  const float* bin  = (const float*)d_in[7];
  const float* Wt   = (const float*)d_in[8];
  const float* bt   = (const float*)d_in[9];
  const float* Wc   = (const float*)d_in[10];
  const float* bc   = (const float*)d_in[11];
  const float* Wout = (const float*)d_in[12];
  const float* bout = (const float*)d_in[13];

  float* out   = (float*)d_out;
  float* ws    = (float*)d_ws;
  float* cproj = ws;                       // 524288 floats
  float* tpb   = ws + 524288;              // 12800 floats
  float* sched = ws + 524288 + 12800;      // 1600 floats (t*8 layout)
  float* pooled = out;                     // reuse d_out as scratch

  k_poolprep<<<2248, 256, 0, stream>>>(seq, emb, pooled, Wt, bt, bin, tpb, sched);
  k_enc  <<<1024, 256, 0, stream>>>(pooled, W1, b1, W2, b2, Wc, bc, cproj);
  k_ddpm <<<2048, 256, 0, stream>>>(Win, Wout, bout, cproj, tpb, sched, out);
}

// Round 14
// 560.800 us; speedup vs baseline: 1.3540x; 1.3540x over previous
//
#include <hip/hip_runtime.h>
#include <cstdint>

// ---------------------------------------------------------------------------
// DDPM + VAE query encoder, MI355X round 26.
// r25 post-mortem: small-block occupancy raise (39->52%) lost to 4x MFMA/LDS
// duplication -> 714 us. Occupancy-chasing is 0-for-3 (r14/r21/r25); the r24
// main loop (425 us) is this decomposition's t-loop floor. r26 attacks the
// ~98 us OUTSIDE the loop (k_poolprep + k_enc + gaps = 19% of wall):
//  - pool -> enc -> cproj fused INTO k_ddpm's prologue, per block (each block
//    needs cproj only for its 16 rows). Bit-identical per-cell accumulation
//    order (same sequential k loops as k_pool/k_enc) -> same floats.
//  - LDS overlay: prologue scratch (pooled/h/mu/cp, 28 KB) aliases the main
//    loop's X/H/nbuf (17.9 KB) via a byte-addressed shared block; cp pulled
//    to registers before the alias flips.
//  - k_prep stays standalone (globally consumed). Launches 3 -> 2.
// Main t-loop is byte-identical to r24. absmax unchanged.
// ---------------------------------------------------------------------------

#define DEVI __device__ __forceinline__

typedef __attribute__((ext_vector_type(8))) short short8;
typedef __attribute__((ext_vector_type(4))) float f32x4;

DEVI void threefry2x32(uint32_t k0, uint32_t k1, uint32_t x0, uint32_t x1,
                       uint32_t &o0, uint32_t &o1)
{
  const uint32_t ks2 = k0 ^ k1 ^ 0x1BD11BDAu;
  x0 += k0; x1 += k1;
#define TFR(r) { x0 += x1; x1 = __builtin_rotateleft32(x1, r); x1 ^= x0; }
  TFR(13u) TFR(15u) TFR(26u) TFR(6u)   x0 += k1;  x1 += ks2 + 1u;
  TFR(17u) TFR(29u) TFR(16u) TFR(24u)  x0 += ks2; x1 += k0 + 2u;
  TFR(13u) TFR(15u) TFR(26u) TFR(6u)   x0 += k0;  x1 += k1 + 3u;
  TFR(17u) TFR(29u) TFR(16u) TFR(24u)  x0 += k1;  x1 += ks2 + 4u;
  TFR(13u) TFR(15u) TFR(26u) TFR(6u)   x0 += ks2; x1 += k0 + 5u;
#undef TFR
  o0 = x0; o1 = x1;
}

DEVI uint32_t jax_random_bits32(uint32_t k0, uint32_t k1, uint32_t j)
{
  uint32_t a, b;
  threefry2x32(k0, k1, 0u, j, a, b);
  return a ^ b;
}

DEVI float jax_bits_to_normal(uint32_t bits)
{
  const float LO = -0.99999994f;
  float f = __uint_as_float((bits >> 9) | 0x3f800000u) - 1.0f;
  float u = fmaxf(LO, f * 2.0f + LO);
  float w = -__logf((1.0f - u) * (1.0f + u));
  float p;
  if (w < 5.0f) {
    w = w - 2.5f;
    p =              2.81022636e-08f;
    p = fmaf(p, w,   3.43273939e-07f);
    p = fmaf(p, w,  -3.5233877e-06f);
    p = fmaf(p, w,  -4.39150654e-06f);
    p = fmaf(p, w,   0.00021858087f);
    p = fmaf(p, w,  -0.00125372503f);
    p = fmaf(p, w,  -0.00417768164f);
    p = fmaf(p, w,   0.246640727f);
    p = fmaf(p, w,   1.50140941f);
  } else {
    w = sqrtf(w) - 3.0f;
    p =             -0.000200214257f;
    p = fmaf(p, w,   0.000100950558f);
    p = fmaf(p, w,   0.00134934322f);
    p = fmaf(p, w,  -0.00367342844f);
    p = fmaf(p, w,   0.00573950773f);
    p = fmaf(p, w,  -0.0076224613f);
    p = fmaf(p, w,   0.00943887047f);
    p = fmaf(p, w,   1.00167406f);
    p = fmaf(p, w,   2.83297682f);
  }
  return 1.41421356237f * (p * u);
}

DEVI short bf16_hi_trunc(float x) { return (short)(__float_as_uint(x) >> 16); }
DEVI float bf16_to_f32(short h)
{
  return __uint_as_float(((uint32_t)(unsigned short)h) << 16);
}
DEVI void split_bf16(float x, short &h, short &l)
{
  h = bf16_hi_trunc(x);
  float r = x - bf16_to_f32(h);
  l = bf16_hi_trunc(r);
}

// 8-short fragment from 16B-aligned LDS (stride-72 rows): one b128 read.
DEVI short8 ld_frag16(const short* p)
{
  union { int4 v; short8 s; } u;
  u.v = *(const int4*)p;
  return u.s;
}

// ---------------------------------------------------------------------------
// k_prep: 200 blocks x 64 threads. Block t computes sched[t*8+..] AND
// tpb[t][d] = temb(t)@W_t + b_t + b_in. (Globally consumed -> standalone.)
__global__ __launch_bounds__(64)
void k_prep(const float* __restrict__ Wt, const float* __restrict__ bt,
            const float* __restrict__ bin, float* __restrict__ tpb,
            float* __restrict__ sched)
{
  __shared__ float temb[64];
  const int t = blockIdx.x;
  const int d = threadIdx.x;
  const float lg = logf(10000.0f);
  {
    int i = d & 31;
    float fr  = expf((-lg * (float)i) / 32.0f);
    float ang = (float)t * fr;
    temb[d] = (d < 32) ? cosf(ang) : sinf(ang);
  }
  if (d == 0) {
    const float start = (float)(5.0 * 1e-4);
    const float stop  = (float)(5.0 * 0.02);
    const float delta = stop - start;
    float prod = 1.f, acp_prev = 1.f, beta = 0.f, alpha = 1.f;
    for (int i = 0; i <= t; ++i) {
      beta  = start + ((float)i * delta) / 199.0f;
      alpha = 1.0f - beta;
      acp_prev = prod;
      prod = prod * alpha;
    }
    float acp = prod;
    float om  = 1.0f - acp;
    sched[t * 8 + 0] = sqrtf(1.0f / acp);
    sched[t * 8 + 1] = sqrtf(1.0f / acp - 1.0f);
    sched[t * 8 + 2] = beta * sqrtf(acp_prev) / om;
    sched[t * 8 + 3] = (1.0f - acp_prev) * sqrtf(alpha) / om;
    float pv = beta * (1.0f - acp_prev) / om;
    sched[t * 8 + 4] = (t > 0) ? sqrtf(pv) : 0.0f;
    uint32_t fk0, fk1;
    threefry2x32(0u, 2u, 0u, (uint32_t)t, fk0, fk1);
    ((uint32_t*)sched)[t * 8 + 5] = fk0;
    ((uint32_t*)sched)[t * 8 + 6] = fk1;
  }
  __syncthreads();
  float acc = bt[d] + bin[d];
  for (int k = 0; k < 64; ++k)
    acc = fmaf(temb[k], Wt[k * 64 + d], acc);
  tpb[t * 64 + d] = acc;
}

// ---------------------------------------------------------------------------
// K_ddpm: 512 blocks x 512 threads (8 waves). Block owns 16 rows.
// PROLOGUE (fused pool->enc->cproj, bit-identical accumulation order):
//   pool 2 cells/thr, h 8 cells/thr, mu 2, cp 2 -> cp pulled to registers.
//   LDS scratch (28 KB) aliases the main loop's X/H/nbuf region.
// MAIN LOOP: byte-identical to r24. Waves 0-3 GEMV (full-K, weights in
//   regs); ALL 8 waves 2 noise draws/lane/step (bits segA, erfinv segB),
//   producer cells cb = w*128 + lane*2.
#define XLDW  72   // X/H row stride (shorts); 144 B -> 16B-aligned frags
#define NBW   68   // nbuf row stride (floats)

__global__
__attribute__((amdgpu_flat_work_group_size(512, 512), amdgpu_waves_per_eu(4, 4)))
void k_ddpm(const int* __restrict__ seq, const float* __restrict__ emb,
            const float* __restrict__ W1, const float* __restrict__ b1,
            const float* __restrict__ W2, const float* __restrict__ b2,
            const float* __restrict__ Wc, const float* __restrict__ bc,
            const float* __restrict__ Win, const float* __restrict__ Wout,
            const float* __restrict__ bout,
            const float* __restrict__ tpb, const float* __restrict__ sched,
            float* __restrict__ out)
{
  // 28672 B: prologue {pool 4K | h 16K | mu 4K | cp 4K} then aliased by
  // main-loop {Xh 2304 | Xl 2304 | Hh 2304 | Hl 2304 | nbuf 8704} = 17920.
  __shared__ __align__(16) char smem[28672];

  const int tid  = threadIdx.x;
  const int lane = tid & 63;
  const int w    = tid >> 6;
  const bool gemv = (w < 4);
  const int r0g  = blockIdx.x * 16;
  const uint32_t* su = (const uint32_t*)sched;

  // ---- GEMV-wave ids
  const int nt   = w & 3;
  const int nn   = lane & 15;
  const int quad = lane >> 4;
  const int dim  = nt * 16 + nn;
  const int arow = nn;
  const int kq0  = quad * 8;
  const int kq1  = 32 + quad * 8;
  const int rowb = quad * 4;                       // owned rows rowb..rowb+3

  // ---- producer ids (ALL waves): 2 consecutive cells
  const int cb   = w * 128 + lane * 2;             // cell base (row*64+dim)
  const uint32_t jn = (uint32_t)(r0g * 64 + cb);   // global noise index base
  const int nrow = cb >> 6;
  const int ndim = cb & 63;

  // =========================================================================
  // PROLOGUE: pool -> h -> mu -> cp (per-cell order identical to k_pool/k_enc)
  // =========================================================================
  {
    float* pool_s = (float*)smem;                  // [16][64]
    float* h_s    = (float*)(smem + 4096);         // [16][256]
    float* mu_s   = (float*)(smem + 20480);        // [16][64]
    float* cp_s   = (float*)(smem + 24576);        // [16][64]

#pragma unroll
    for (int i = 0; i < 2; ++i) {                  // pool: 2 cells/thread
      int c = tid + i * 512;
      int row = c >> 6, d = c & 63;
      const int* rowp = seq + (r0g + row) * 100;
      float s = 0.f; int cnt = 0;
      for (int l = 0; l < 100; ++l) {
        int id = rowp[l];
        cnt += (id != 0);
        s += emb[id * 64 + d];
      }
      pool_s[row * 64 + d] = s / sqrtf((float)cnt);
    }
    __syncthreads();

#pragma unroll
    for (int i = 0; i < 8; ++i) {                  // h: 8 cells/thread
      int c = tid + i * 512;
      int row = c >> 8, j = c & 255;
      float a = b1[j];
      for (int k = 0; k < 64; ++k)
        a = fmaf(pool_s[row * 64 + k], W1[k * 256 + j], a);
      h_s[row * 256 + j] = fmaxf(a, 0.f);
    }
    __syncthreads();

#pragma unroll
    for (int i = 0; i < 2; ++i) {                  // mu: 2 cells/thread
      int c = tid + i * 512;
      int row = c >> 6, j = c & 63;
      float a = b2[j];
      for (int k = 0; k < 256; ++k)
        a = fmaf(h_s[row * 256 + k], W2[k * 128 + j], a);
      mu_s[row * 64 + j] = a;
    }
    __syncthreads();

#pragma unroll
    for (int i = 0; i < 2; ++i) {                  // cp: 2 cells/thread
      int c = tid + i * 512;
      int row = c >> 6, j = c & 63;
      float a = bc[j];
      for (int k = 0; k < 64; ++k)
        a = fmaf(mu_s[row * 64 + k], Wc[k * 64 + j], a);
      cp_s[row * 64 + j] = a;
    }
    __syncthreads();
    // fall through: cp_s read below, then alias flips
  }

  float cp[4] = {0.f, 0.f, 0.f, 0.f};
  if (gemv) {
    const float* cp_s = (const float*)(smem + 24576);
#pragma unroll
    for (int r = 0; r < 4; ++r) cp[r] = cp_s[(rowb + r) * 64 + dim];
  }
  __syncthreads();   // all cp reads done -> smem reusable

  // =========================================================================
  // MAIN LOOP (r24, byte-identical structure)
  // =========================================================================
  short* Xh = (short*)smem;                        // [16*72]
  short* Xl = (short*)(smem + 2304);
  short* Hh = (short*)(smem + 4608);
  short* Hl = (short*)(smem + 6912);
  float* nbuf = (float*)(smem + 9216);             // [2*16*68]
  float* nb_w = &nbuf[nrow * NBW + ndim];          // + buf*16*NBW at use

  // ---- weight B-fragments -> registers
  short8 wiH0, wiL0, wiH1, wiL1, woH0, woL0, woH1, woL1;
  float xo[4] = {0.f, 0.f, 0.f, 0.f};
  float bo = 0.f, tp = 0.f;
  uint32_t j0 = 0;

  if (gemv) {
#pragma unroll
    for (int j = 0; j < 8; ++j) {
      short h, l;
      split_bf16(Win[(kq0 + j) * 64 + dim], h, l);  wiH0[j] = h; wiL0[j] = l;
      split_bf16(Win[(kq1 + j) * 64 + dim], h, l);  wiH1[j] = h; wiL1[j] = l;
      split_bf16(Wout[(kq0 + j) * 64 + dim], h, l); woH0[j] = h; woL0[j] = l;
      split_bf16(Wout[(kq1 + j) * 64 + dim], h, l); woH1[j] = h; woL1[j] = l;
    }
    bo = bout[dim];
    j0 = (uint32_t)((r0g + rowb) * 64 + dim);
#pragma unroll
    for (int r = 0; r < 4; ++r) {
      xo[r] = jax_bits_to_normal(jax_random_bits32(0u, 1u, j0 + r * 64u));
      short h, l;
      split_bf16(xo[r], h, l);
      Xh[(rowb + r) * XLDW + dim] = h; Xl[(rowb + r) * XLDW + dim] = l;
    }
    tp = tpb[199 * 64 + dim];
  }
  // prologue noise for t=199 into nbuf[1]: ALL waves, 2 cells each
  {
    const uint32_t fk0 = su[199 * 8 + 5];
    const uint32_t fk1 = su[199 * 8 + 6];
    float* d = nb_w + 16 * NBW;                    // buf 1
    d[0] = jax_bits_to_normal(jax_random_bits32(fk0, fk1, jn + 0u));
    d[1] = jax_bits_to_normal(jax_random_bits32(fk0, fk1, jn + 1u));
  }
  __syncthreads();

#pragma unroll 1
  for (int t = 199; t >= 0; --t) {
    // draw setup for step t-1
    uint32_t gk0 = 0, gk1 = 0;
    float* nd = nullptr;
    if (t > 0) {
      gk0 = su[(t - 1) * 8 + 5];
      gk1 = su[(t - 1) * 8 + 6];
      nd = nb_w + ((t - 1) & 1) * 16 * NBW;
    }

    float sr = 0.f, srm1 = 0.f, c1 = 0.f, c2 = 0.f, sg = 0.f, tpn = 0.f;
    f32x4 acc;

    if (gemv) {
      sr   = sched[t * 8 + 0];
      srm1 = sched[t * 8 + 1];
      c1   = sched[t * 8 + 2];
      c2   = sched[t * 8 + 3];
      sg   = sched[t * 8 + 4];

      // ---- phase A: in-GEMV, full K=64, bias in all 4 owned slots
#pragma unroll
      for (int r = 0; r < 4; ++r) acc[r] = tp + cp[r];
      {
        short8 xh0 = ld_frag16(&Xh[arow * XLDW + kq0]);
        short8 xl0 = ld_frag16(&Xl[arow * XLDW + kq0]);
        short8 xh1 = ld_frag16(&Xh[arow * XLDW + kq1]);
        short8 xl1 = ld_frag16(&Xl[arow * XLDW + kq1]);
        acc = __builtin_amdgcn_mfma_f32_16x16x32_bf16(xl0, wiH0, acc, 0, 0, 0);
        acc = __builtin_amdgcn_mfma_f32_16x16x32_bf16(xh0, wiL0, acc, 0, 0, 0);
        acc = __builtin_amdgcn_mfma_f32_16x16x32_bf16(xh0, wiH0, acc, 0, 0, 0);
        acc = __builtin_amdgcn_mfma_f32_16x16x32_bf16(xl1, wiH1, acc, 0, 0, 0);
        acc = __builtin_amdgcn_mfma_f32_16x16x32_bf16(xh1, wiL1, acc, 0, 0, 0);
        acc = __builtin_amdgcn_mfma_f32_16x16x32_bf16(xh1, wiH1, acc, 0, 0, 0);
      }
#pragma unroll
      for (int r = 0; r < 4; ++r) {
        float v = acc[r];
        v = v * __builtin_amdgcn_rcpf(1.0f + __expf(-v));
        short h, l;
        split_bf16(v, h, l);
        Hh[(rowb + r) * XLDW + dim] = h; Hl[(rowb + r) * XLDW + dim] = l;
      }
      int tn = (t > 0) ? (t - 1) : 0;
      tpn = tpb[tn * 64 + dim];                    // prefetch next tp
    }
    // segA (all 8 waves): BOTH threefry chains for step t-1 (bits only)
    uint32_t b0 = 0, b1v = 0;
    if (t > 0) {
      b0  = jax_random_bits32(gk0, gk1, jn + 0u);
      b1v = jax_random_bits32(gk0, gk1, jn + 1u);
    }
    __syncthreads();                                // B1

    if (gemv) {
      // noise for this step (buf t&1 fully written by end of iter t+1)
      float n[4];
      const float* nr = &nbuf[(t & 1) * 16 * NBW + rowb * NBW + dim];
#pragma unroll
      for (int r = 0; r < 4; ++r) n[r] = nr[r * NBW];

      // ---- phase B: out-GEMV, full K=64, update 4 cells, restage X
      f32x4 eac;
#pragma unroll
      for (int r = 0; r < 4; ++r) eac[r] = bo;
      {
        short8 hh0 = ld_frag16(&Hh[arow * XLDW + kq0]);
        short8 hl0 = ld_frag16(&Hl[arow * XLDW + kq0]);
        short8 hh1 = ld_frag16(&Hh[arow * XLDW + kq1]);
        short8 hl1 = ld_frag16(&Hl[arow * XLDW + kq1]);
        eac = __builtin_amdgcn_mfma_f32_16x16x32_bf16(hl0, woH0, eac, 0, 0, 0);
        eac = __builtin_amdgcn_mfma_f32_16x16x32_bf16(hh0, woL0, eac, 0, 0, 0);
        eac = __builtin_amdgcn_mfma_f32_16x16x32_bf16(hh0, woH0, eac, 0, 0, 0);
        eac = __builtin_amdgcn_mfma_f32_16x16x32_bf16(hl1, woH1, eac, 0, 0, 0);
        eac = __builtin_amdgcn_mfma_f32_16x16x32_bf16(hh1, woL1, eac, 0, 0, 0);
        eac = __builtin_amdgcn_mfma_f32_16x16x32_bf16(hh1, woH1, eac, 0, 0, 0);
      }
#pragma unroll
      for (int r = 0; r < 4; ++r) {
        float xc = fminf(1.f, fmaxf(-1.f, sr * xo[r] - srm1 * eac[r]));
        xo[r] = c1 * xc + c2 * xo[r] + sg * n[r];
        short h, l;
        split_bf16(xo[r], h, l);
        Xh[(rowb + r) * XLDW + dim] = h; Xl[(rowb + r) * XLDW + dim] = l;
      }
      tp = tpn;
    }
    // segB (all 8 waves): BOTH erfinv chains + nbuf write
    if (t > 0) {
      nd[0] = jax_bits_to_normal(b0);
      nd[1] = jax_bits_to_normal(b1v);
    }
    __syncthreads();                                // B2
  }

  if (gemv) {
#pragma unroll
    for (int r = 0; r < 4; ++r) out[j0 + r * 64u] = xo[r];
  }
}

// ---------------------------------------------------------------------------
extern "C" void kernel_launch(void* const* d_in, const int* in_sizes, int n_in,
                              void* d_out, int out_size, void* d_ws, size_t ws_size,
                              hipStream_t stream)
{
  const int*   seq  = (const int*)  d_in[0];
  const float* emb  = (const float*)d_in[1];
  const float* W1   = (const float*)d_in[2];
  const float* b1   = (const float*)d_in[3];
  const float* W2   = (const float*)d_in[4];
  const float* b2   = (const float*)d_in[5];
  const float* Win  = (const float*)d_in[6];
  const float* bin  = (const float*)d_in[7];
  const float* Wt   = (const float*)d_in[8];
  const float* bt   = (const float*)d_in[9];
  const float* Wc   = (const float*)d_in[10];
  const float* bc   = (const float*)d_in[11];
  const float* Wout = (const float*)d_in[12];
  const float* bout = (const float*)d_in[13];

  float* out   = (float*)d_out;
  float* ws    = (float*)d_ws;
  float* tpb   = ws;                       // 12800 floats
  float* sched = ws + 12800;               // 1600 floats (t*8 layout)

  k_prep <<<200, 64, 0, stream>>>(Wt, bt, bin, tpb, sched);
  k_ddpm <<<512, 512, 0, stream>>>(seq, emb, W1, b1, W2, b2, Wc, bc,
                                   Win, Wout, bout, tpb, sched, out);
}

// Round 15
// 547.795 us; speedup vs baseline: 1.3861x; 1.0237x over previous
//
#include <hip/hip_runtime.h>
#include <cstdint>

// ---------------------------------------------------------------------------
// DDPM + VAE query encoder, MI355X round 27.
// r26 post-mortem: fusing pool/enc INTO k_ddpm dragged high-parallelism work
// into the residency-limited kernel (512 blocks re-read W1/W2/Wc -> FETCH
// 90 MB; prologue ran at 2 blocks/CU) -> 560 us. Lesson: fuse at MATCHING
// parallelism. r27: fuse pool->enc only (row-local dependency) in one
// 1024-block x 256-thr kernel (pool to LDS, enc from LDS, cp to cproj),
// prep blocks tacked on (r24 pattern). k_ddpm reverts to r24 BYTE-IDENTICAL
// (425 us proven). Launches 3 -> 2; pooled HBM round-trip gone.
// Arithmetic bit-exact (r26 proved the per-cell loops; only staging moved).
// ---------------------------------------------------------------------------

#define DEVI __device__ __forceinline__

typedef __attribute__((ext_vector_type(8))) short short8;
typedef __attribute__((ext_vector_type(4))) float f32x4;

DEVI void threefry2x32(uint32_t k0, uint32_t k1, uint32_t x0, uint32_t x1,
                       uint32_t &o0, uint32_t &o1)
{
  const uint32_t ks2 = k0 ^ k1 ^ 0x1BD11BDAu;
  x0 += k0; x1 += k1;
#define TFR(r) { x0 += x1; x1 = __builtin_rotateleft32(x1, r); x1 ^= x0; }
  TFR(13u) TFR(15u) TFR(26u) TFR(6u)   x0 += k1;  x1 += ks2 + 1u;
  TFR(17u) TFR(29u) TFR(16u) TFR(24u)  x0 += ks2; x1 += k0 + 2u;
  TFR(13u) TFR(15u) TFR(26u) TFR(6u)   x0 += k0;  x1 += k1 + 3u;
  TFR(17u) TFR(29u) TFR(16u) TFR(24u)  x0 += k1;  x1 += ks2 + 4u;
  TFR(13u) TFR(15u) TFR(26u) TFR(6u)   x0 += ks2; x1 += k0 + 5u;
#undef TFR
  o0 = x0; o1 = x1;
}

DEVI uint32_t jax_random_bits32(uint32_t k0, uint32_t k1, uint32_t j)
{
  uint32_t a, b;
  threefry2x32(k0, k1, 0u, j, a, b);
  return a ^ b;
}

DEVI float jax_bits_to_normal(uint32_t bits)
{
  const float LO = -0.99999994f;
  float f = __uint_as_float((bits >> 9) | 0x3f800000u) - 1.0f;
  float u = fmaxf(LO, f * 2.0f + LO);
  float w = -__logf((1.0f - u) * (1.0f + u));
  float p;
  if (w < 5.0f) {
    w = w - 2.5f;
    p =              2.81022636e-08f;
    p = fmaf(p, w,   3.43273939e-07f);
    p = fmaf(p, w,  -3.5233877e-06f);
    p = fmaf(p, w,  -4.39150654e-06f);
    p = fmaf(p, w,   0.00021858087f);
    p = fmaf(p, w,  -0.00125372503f);
    p = fmaf(p, w,  -0.00417768164f);
    p = fmaf(p, w,   0.246640727f);
    p = fmaf(p, w,   1.50140941f);
  } else {
    w = sqrtf(w) - 3.0f;
    p =             -0.000200214257f;
    p = fmaf(p, w,   0.000100950558f);
    p = fmaf(p, w,   0.00134934322f);
    p = fmaf(p, w,  -0.00367342844f);
    p = fmaf(p, w,   0.00573950773f);
    p = fmaf(p, w,  -0.0076224613f);
    p = fmaf(p, w,   0.00943887047f);
    p = fmaf(p, w,   1.00167406f);
    p = fmaf(p, w,   2.83297682f);
  }
  return 1.41421356237f * (p * u);
}

DEVI short bf16_hi_trunc(float x) { return (short)(__float_as_uint(x) >> 16); }
DEVI float bf16_to_f32(short h)
{
  return __uint_as_float(((uint32_t)(unsigned short)h) << 16);
}
DEVI void split_bf16(float x, short &h, short &l)
{
  h = bf16_hi_trunc(x);
  float r = x - bf16_to_f32(h);
  l = bf16_hi_trunc(r);
}

// 8-short fragment from 16B-aligned LDS (stride-72 rows): one b128 read.
DEVI short8 ld_frag16(const short* p)
{
  union { int4 v; short8 s; } u;
  u.v = *(const int4*)p;
  return u.s;
}

// ---------------------------------------------------------------------------
// k_poolenc: blocks [0,1024) = fused pool->enc for rows 8b..8b+7 (pool to
// LDS, enc from LDS, cp to cproj; per-cell loops bit-identical to the
// original k_pool/k_enc). Blocks [1024,1224) = prep for t = blockIdx-1024.
__global__ __launch_bounds__(256)
void k_poolenc(const int* __restrict__ seq, const float* __restrict__ emb,
               const float* __restrict__ W1, const float* __restrict__ b1,
               const float* __restrict__ W2, const float* __restrict__ b2,
               const float* __restrict__ Wc, const float* __restrict__ bc,
               float* __restrict__ cproj,
               const float* __restrict__ Wt, const float* __restrict__ bt,
               const float* __restrict__ bin, float* __restrict__ tpb,
               float* __restrict__ sched)
{
  __shared__ float p_s[8 * 64];
  __shared__ float h_s[8 * 256];
  __shared__ float mu_s[8 * 64];
  const int tid = threadIdx.x;

  if (blockIdx.x < 1024u) {
    const int r0 = blockIdx.x * 8;

    // pool: 2 cells/thread, per-cell serial l-loop (== k_pool order)
#pragma unroll
    for (int i = 0; i < 2; ++i) {
      int c = tid + i * 256;
      int row = c >> 6, d = c & 63;
      const int* rowp = seq + (r0 + row) * 100;
      float s = 0.f; int cnt = 0;
      for (int l = 0; l < 100; ++l) {
        int id = rowp[l];
        cnt += (id != 0);
        s += emb[id * 64 + d];
      }
      p_s[row * 64 + d] = s / sqrtf((float)cnt);
    }
    __syncthreads();

    // h: 8 cells/thread (== k_enc per-cell k order)
#pragma unroll
    for (int i = 0; i < 8; ++i) {
      int c = tid + i * 256;
      int row = c >> 8, j = c & 255;
      float a = b1[j];
      for (int k = 0; k < 64; ++k)
        a = fmaf(p_s[row * 64 + k], W1[k * 256 + j], a);
      h_s[row * 256 + j] = fmaxf(a, 0.f);
    }
    __syncthreads();

    // mu: 2 cells/thread
#pragma unroll
    for (int i = 0; i < 2; ++i) {
      int c = tid + i * 256;
      int row = c >> 6, j = c & 63;
      float a = b2[j];
      for (int k = 0; k < 256; ++k)
        a = fmaf(h_s[row * 256 + k], W2[k * 128 + j], a);
      mu_s[row * 64 + j] = a;
    }
    __syncthreads();

    // cp: 2 cells/thread -> global cproj
#pragma unroll
    for (int i = 0; i < 2; ++i) {
      int c = tid + i * 256;
      int row = c >> 6, j = c & 63;
      float a = bc[j];
      for (int k = 0; k < 64; ++k)
        a = fmaf(mu_s[row * 64 + k], Wc[k * 64 + j], a);
      cproj[(r0 + row) * 64 + j] = a;
    }
  } else {
    // prep for t = blockIdx - 1024 (r24 pattern: 64 of 256 threads active)
    __shared__ float temb[64];
    const int t = blockIdx.x - 1024;
    const int d = tid;
    if (d < 64) {
      const float lg = logf(10000.0f);
      int i = d & 31;
      float fr  = expf((-lg * (float)i) / 32.0f);
      float ang = (float)t * fr;
      temb[d] = (d < 32) ? cosf(ang) : sinf(ang);
      if (d == 0) {
        const float start = (float)(5.0 * 1e-4);
        const float stop  = (float)(5.0 * 0.02);
        const float delta = stop - start;
        float prod = 1.f, acp_prev = 1.f, beta = 0.f, alpha = 1.f;
        for (int i2 = 0; i2 <= t; ++i2) {
          beta  = start + ((float)i2 * delta) / 199.0f;
          alpha = 1.0f - beta;
          acp_prev = prod;
          prod = prod * alpha;
        }
        float acp = prod;
        float om  = 1.0f - acp;
        sched[t * 8 + 0] = sqrtf(1.0f / acp);
        sched[t * 8 + 1] = sqrtf(1.0f / acp - 1.0f);
        sched[t * 8 + 2] = beta * sqrtf(acp_prev) / om;
        sched[t * 8 + 3] = (1.0f - acp_prev) * sqrtf(alpha) / om;
        float pv = beta * (1.0f - acp_prev) / om;
        sched[t * 8 + 4] = (t > 0) ? sqrtf(pv) : 0.0f;
        uint32_t fk0, fk1;
        threefry2x32(0u, 2u, 0u, (uint32_t)t, fk0, fk1);
        ((uint32_t*)sched)[t * 8 + 5] = fk0;
        ((uint32_t*)sched)[t * 8 + 6] = fk1;
      }
    }
    __syncthreads();
    if (d < 64) {
      float acc = bt[d] + bin[d];
      for (int k = 0; k < 64; ++k)
        acc = fmaf(temb[k], Wt[k * 64 + d], acc);
      tpb[t * 64 + d] = acc;
    }
  }
}

// ---------------------------------------------------------------------------
// K_ddpm: 512 blocks x 512 threads (8 waves). Block owns 16 rows.
// BYTE-IDENTICAL to r24 (425 us proven). Waves 0-3 GEMV (full-K, weights
// in regs); ALL 8 waves 2 noise draws/lane/step (bits segA, erfinv segB),
// producer cells cb = w*128 + lane*2.
#define XLDW  72   // X/H row stride (shorts); 144 B -> 16B-aligned frags
#define NBW   68   // nbuf row stride (floats)

__global__
__attribute__((amdgpu_flat_work_group_size(512, 512), amdgpu_waves_per_eu(4, 4)))
void k_ddpm(const float* __restrict__ Win, const float* __restrict__ Wout,
            const float* __restrict__ bout,
            const float* __restrict__ cproj, const float* __restrict__ tpb,
            const float* __restrict__ sched, float* __restrict__ out)
{
  __shared__ __align__(16) short Xh[16 * XLDW], Xl[16 * XLDW];
  __shared__ __align__(16) short Hh[16 * XLDW], Hl[16 * XLDW];
  __shared__ __align__(16) float nbuf[2 * 16 * NBW];
  // total: 4*2304 + 8704 = 17920 B

  const int tid  = threadIdx.x;
  const int lane = tid & 63;
  const int w    = tid >> 6;
  const bool gemv = (w < 4);
  const int r0g  = blockIdx.x * 16;
  const uint32_t* su = (const uint32_t*)sched;

  // ---- GEMV-wave ids
  const int nt   = w & 3;
  const int nn   = lane & 15;
  const int quad = lane >> 4;
  const int dim  = nt * 16 + nn;
  const int arow = nn;
  const int kq0  = quad * 8;
  const int kq1  = 32 + quad * 8;
  const int rowb = quad * 4;                       // owned rows rowb..rowb+3

  // ---- producer ids (ALL waves): 2 consecutive cells
  const int cb   = w * 128 + lane * 2;             // cell base (row*64+dim)
  const uint32_t jn = (uint32_t)(r0g * 64 + cb);   // global noise index base
  const int nrow = cb >> 6;
  const int ndim = cb & 63;
  float* nb_w = &nbuf[nrow * NBW + ndim];          // + buf*16*NBW at use

  // ---- GEMV state
  short8 wiH0, wiL0, wiH1, wiL1, woH0, woL0, woH1, woL1;
  float cp[4] = {0.f, 0.f, 0.f, 0.f}, xo[4] = {0.f, 0.f, 0.f, 0.f};
  float bo = 0.f, tp = 0.f;
  uint32_t j0 = 0;

  if (gemv) {
#pragma unroll
    for (int j = 0; j < 8; ++j) {
      short h, l;
      split_bf16(Win[(kq0 + j) * 64 + dim], h, l);  wiH0[j] = h; wiL0[j] = l;
      split_bf16(Win[(kq1 + j) * 64 + dim], h, l);  wiH1[j] = h; wiL1[j] = l;
      split_bf16(Wout[(kq0 + j) * 64 + dim], h, l); woH0[j] = h; woL0[j] = l;
      split_bf16(Wout[(kq1 + j) * 64 + dim], h, l); woH1[j] = h; woL1[j] = l;
    }
    bo = bout[dim];
    j0 = (uint32_t)((r0g + rowb) * 64 + dim);
#pragma unroll
    for (int r = 0; r < 4; ++r) cp[r] = cproj[j0 + r * 64u];
#pragma unroll
    for (int r = 0; r < 4; ++r) {
      xo[r] = jax_bits_to_normal(jax_random_bits32(0u, 1u, j0 + r * 64u));
      short h, l;
      split_bf16(xo[r], h, l);
      Xh[(rowb + r) * XLDW + dim] = h; Xl[(rowb + r) * XLDW + dim] = l;
    }
    tp = tpb[199 * 64 + dim];
  }
  // prologue noise for t=199 into nbuf[1]: ALL waves, 2 cells each
  {
    const uint32_t fk0 = su[199 * 8 + 5];
    const uint32_t fk1 = su[199 * 8 + 6];
    float* d = nb_w + 16 * NBW;                    // buf 1
    d[0] = jax_bits_to_normal(jax_random_bits32(fk0, fk1, jn + 0u));
    d[1] = jax_bits_to_normal(jax_random_bits32(fk0, fk1, jn + 1u));
  }
  __syncthreads();

#pragma unroll 1
  for (int t = 199; t >= 0; --t) {
    // draw setup for step t-1
    uint32_t gk0 = 0, gk1 = 0;
    float* nd = nullptr;
    if (t > 0) {
      gk0 = su[(t - 1) * 8 + 5];
      gk1 = su[(t - 1) * 8 + 6];
      nd = nb_w + ((t - 1) & 1) * 16 * NBW;
    }

    float sr = 0.f, srm1 = 0.f, c1 = 0.f, c2 = 0.f, sg = 0.f, tpn = 0.f;
    f32x4 acc;

    if (gemv) {
      sr   = sched[t * 8 + 0];
      srm1 = sched[t * 8 + 1];
      c1   = sched[t * 8 + 2];
      c2   = sched[t * 8 + 3];
      sg   = sched[t * 8 + 4];

      // ---- phase A: in-GEMV, full K=64, bias in all 4 owned slots
#pragma unroll
      for (int r = 0; r < 4; ++r) acc[r] = tp + cp[r];
      {
        short8 xh0 = ld_frag16(&Xh[arow * XLDW + kq0]);
        short8 xl0 = ld_frag16(&Xl[arow * XLDW + kq0]);
        short8 xh1 = ld_frag16(&Xh[arow * XLDW + kq1]);
        short8 xl1 = ld_frag16(&Xl[arow * XLDW + kq1]);
        acc = __builtin_amdgcn_mfma_f32_16x16x32_bf16(xl0, wiH0, acc, 0, 0, 0);
        acc = __builtin_amdgcn_mfma_f32_16x16x32_bf16(xh0, wiL0, acc, 0, 0, 0);
        acc = __builtin_amdgcn_mfma_f32_16x16x32_bf16(xh0, wiH0, acc, 0, 0, 0);
        acc = __builtin_amdgcn_mfma_f32_16x16x32_bf16(xl1, wiH1, acc, 0, 0, 0);
        acc = __builtin_amdgcn_mfma_f32_16x16x32_bf16(xh1, wiL1, acc, 0, 0, 0);
        acc = __builtin_amdgcn_mfma_f32_16x16x32_bf16(xh1, wiH1, acc, 0, 0, 0);
      }
#pragma unroll
      for (int r = 0; r < 4; ++r) {
        float v = acc[r];
        v = v * __builtin_amdgcn_rcpf(1.0f + __expf(-v));
        short h, l;
        split_bf16(v, h, l);
        Hh[(rowb + r) * XLDW + dim] = h; Hl[(rowb + r) * XLDW + dim] = l;
      }
      int tn = (t > 0) ? (t - 1) : 0;
      tpn = tpb[tn * 64 + dim];                    // prefetch next tp
    }
    // segA (all 8 waves): BOTH threefry chains for step t-1 (bits only)
    uint32_t b0 = 0, b1v = 0;
    if (t > 0) {
      b0  = jax_random_bits32(gk0, gk1, jn + 0u);
      b1v = jax_random_bits32(gk0, gk1, jn + 1u);
    }
    __syncthreads();                                // B1

    if (gemv) {
      // noise for this step (buf t&1 fully written by end of iter t+1)
      float n[4];
      const float* nr = &nbuf[(t & 1) * 16 * NBW + rowb * NBW + dim];
#pragma unroll
      for (int r = 0; r < 4; ++r) n[r] = nr[r * NBW];

      // ---- phase B: out-GEMV, full K=64, update 4 cells, restage X
      f32x4 eac;
#pragma unroll
      for (int r = 0; r < 4; ++r) eac[r] = bo;
      {
        short8 hh0 = ld_frag16(&Hh[arow * XLDW + kq0]);
        short8 hl0 = ld_frag16(&Hl[arow * XLDW + kq0]);
        short8 hh1 = ld_frag16(&Hh[arow * XLDW + kq1]);
        short8 hl1 = ld_frag16(&Hl[arow * XLDW + kq1]);
        eac = __builtin_amdgcn_mfma_f32_16x16x32_bf16(hl0, woH0, eac, 0, 0, 0);
        eac = __builtin_amdgcn_mfma_f32_16x16x32_bf16(hh0, woL0, eac, 0, 0, 0);
        eac = __builtin_amdgcn_mfma_f32_16x16x32_bf16(hh0, woH0, eac, 0, 0, 0);
        eac = __builtin_amdgcn_mfma_f32_16x16x32_bf16(hl1, woH1, eac, 0, 0, 0);
        eac = __builtin_amdgcn_mfma_f32_16x16x32_bf16(hh1, woL1, eac, 0, 0, 0);
        eac = __builtin_amdgcn_mfma_f32_16x16x32_bf16(hh1, woH1, eac, 0, 0, 0);
      }
#pragma unroll
      for (int r = 0; r < 4; ++r) {
        float xc = fminf(1.f, fmaxf(-1.f, sr * xo[r] - srm1 * eac[r]));
        xo[r] = c1 * xc + c2 * xo[r] + sg * n[r];
        short h, l;
        split_bf16(xo[r], h, l);
        Xh[(rowb + r) * XLDW + dim] = h; Xl[(rowb + r) * XLDW + dim] = l;
      }
      tp = tpn;
    }
    // segB (all 8 waves): BOTH erfinv chains + nbuf write
    if (t > 0) {
      nd[0] = jax_bits_to_normal(b0);
      nd[1] = jax_bits_to_normal(b1v);
    }
    __syncthreads();                                // B2
  }

  if (gemv) {
#pragma unroll
    for (int r = 0; r < 4; ++r) out[j0 + r * 64u] = xo[r];
  }
}

// ---------------------------------------------------------------------------
extern "C" void kernel_launch(void* const* d_in, const int* in_sizes, int n_in,
                              void* d_out, int out_size, void* d_ws, size_t ws_size,
                              hipStream_t stream)
{
  const int*   seq  = (const int*)  d_in[0];
  const float* emb  = (const float*)d_in[1];
  const float* W1   = (const float*)d_in[2];
  const float* b1   = (const float*)d_in[3];
  const float* W2   = (const float*)d_in[4];
  const float* b2   = (const float*)d_in[5];
  const float* Win  = (const float*)d_in[6];
  const float* bin  = (const float*)d_in[7];
  const float* Wt   = (const float*)d_in[8];
  const float* bt   = (const float*)d_in[9];
  const float* Wc   = (const float*)d_in[10];
  const float* bc   = (const float*)d_in[11];
  const float* Wout = (const float*)d_in[12];
  const float* bout = (const float*)d_in[13];

  float* out   = (float*)d_out;
  float* ws    = (float*)d_ws;
  float* cproj = ws;                       // 524288 floats
  float* tpb   = ws + 524288;              // 12800 floats
  float* sched = ws + 524288 + 12800;      // 1600 floats (t*8 layout)

  k_poolenc<<<1224, 256, 0, stream>>>(seq, emb, W1, b1, W2, b2, Wc, bc,
                                      cproj, Wt, bt, bin, tpb, sched);
  k_ddpm <<<512, 512, 0, stream>>>(Win, Wout, bout, cproj, tpb, sched, out);
}

// Round 16
// 538.371 us; speedup vs baseline: 1.4104x; 1.0175x over previous
//
#include <hip/hip_runtime.h>
#include <cstdint>

// ---------------------------------------------------------------------------
// DDPM + VAE query encoder, MI355X round 28.
// r27 post-mortem: pool->enc fusion direction right, but 256-thread blocks
// HALVED pool parallelism (2 cells x 100 gathers = 200-deep latency chain)
// -> k_poolenc 127 us, total regressed. (30.8ms _ord-38 dispatch = rocprof
// replay artifact; bench dur is clean.) r28: same fusion at 512 threads:
//  - pool: 1 cell/thread (524k threads, 100-gather chain == original k_pool)
//  - h: 4 cells/thread (2x more parallel than original k_enc)
//  - mu/cp: 1 cell/thread
// Per-cell loops identical -> bit-exact. k_ddpm byte-identical to r24/r27
// (420.9 us proven). Launches stay 2.
// ---------------------------------------------------------------------------

#define DEVI __device__ __forceinline__

typedef __attribute__((ext_vector_type(8))) short short8;
typedef __attribute__((ext_vector_type(4))) float f32x4;

DEVI void threefry2x32(uint32_t k0, uint32_t k1, uint32_t x0, uint32_t x1,
                       uint32_t &o0, uint32_t &o1)
{
  const uint32_t ks2 = k0 ^ k1 ^ 0x1BD11BDAu;
  x0 += k0; x1 += k1;
#define TFR(r) { x0 += x1; x1 = __builtin_rotateleft32(x1, r); x1 ^= x0; }
  TFR(13u) TFR(15u) TFR(26u) TFR(6u)   x0 += k1;  x1 += ks2 + 1u;
  TFR(17u) TFR(29u) TFR(16u) TFR(24u)  x0 += ks2; x1 += k0 + 2u;
  TFR(13u) TFR(15u) TFR(26u) TFR(6u)   x0 += k0;  x1 += k1 + 3u;
  TFR(17u) TFR(29u) TFR(16u) TFR(24u)  x0 += k1;  x1 += ks2 + 4u;
  TFR(13u) TFR(15u) TFR(26u) TFR(6u)   x0 += ks2; x1 += k0 + 5u;
#undef TFR
  o0 = x0; o1 = x1;
}

DEVI uint32_t jax_random_bits32(uint32_t k0, uint32_t k1, uint32_t j)
{
  uint32_t a, b;
  threefry2x32(k0, k1, 0u, j, a, b);
  return a ^ b;
}

DEVI float jax_bits_to_normal(uint32_t bits)
{
  const float LO = -0.99999994f;
  float f = __uint_as_float((bits >> 9) | 0x3f800000u) - 1.0f;
  float u = fmaxf(LO, f * 2.0f + LO);
  float w = -__logf((1.0f - u) * (1.0f + u));
  float p;
  if (w < 5.0f) {
    w = w - 2.5f;
    p =              2.81022636e-08f;
    p = fmaf(p, w,   3.43273939e-07f);
    p = fmaf(p, w,  -3.5233877e-06f);
    p = fmaf(p, w,  -4.39150654e-06f);
    p = fmaf(p, w,   0.00021858087f);
    p = fmaf(p, w,  -0.00125372503f);
    p = fmaf(p, w,  -0.00417768164f);
    p = fmaf(p, w,   0.246640727f);
    p = fmaf(p, w,   1.50140941f);
  } else {
    w = sqrtf(w) - 3.0f;
    p =             -0.000200214257f;
    p = fmaf(p, w,   0.000100950558f);
    p = fmaf(p, w,   0.00134934322f);
    p = fmaf(p, w,  -0.00367342844f);
    p = fmaf(p, w,   0.00573950773f);
    p = fmaf(p, w,  -0.0076224613f);
    p = fmaf(p, w,   0.00943887047f);
    p = fmaf(p, w,   1.00167406f);
    p = fmaf(p, w,   2.83297682f);
  }
  return 1.41421356237f * (p * u);
}

DEVI short bf16_hi_trunc(float x) { return (short)(__float_as_uint(x) >> 16); }
DEVI float bf16_to_f32(short h)
{
  return __uint_as_float(((uint32_t)(unsigned short)h) << 16);
}
DEVI void split_bf16(float x, short &h, short &l)
{
  h = bf16_hi_trunc(x);
  float r = x - bf16_to_f32(h);
  l = bf16_hi_trunc(r);
}

// 8-short fragment from 16B-aligned LDS (stride-72 rows): one b128 read.
DEVI short8 ld_frag16(const short* p)
{
  union { int4 v; short8 s; } u;
  u.v = *(const int4*)p;
  return u.s;
}

// ---------------------------------------------------------------------------
// k_poolenc: 512 threads. Blocks [0,1024) = fused pool->enc for rows
// 8b..8b+7 (pool 1 cell/thr, h 4 cells/thr, mu/cp 1 cell/thr; per-cell
// loops bit-identical to original k_pool/k_enc). Blocks [1024,1224) = prep.
__global__ __launch_bounds__(512)
void k_poolenc(const int* __restrict__ seq, const float* __restrict__ emb,
               const float* __restrict__ W1, const float* __restrict__ b1,
               const float* __restrict__ W2, const float* __restrict__ b2,
               const float* __restrict__ Wc, const float* __restrict__ bc,
               float* __restrict__ cproj,
               const float* __restrict__ Wt, const float* __restrict__ bt,
               const float* __restrict__ bin, float* __restrict__ tpb,
               float* __restrict__ sched)
{
  __shared__ float p_s[8 * 64];
  __shared__ float h_s[8 * 256];
  __shared__ float mu_s[8 * 64];
  const int tid = threadIdx.x;

  if (blockIdx.x < 1024u) {
    const int r0 = blockIdx.x * 8;

    // pool: 1 cell/thread (100-gather chain, == original k_pool)
    {
      int row = tid >> 6, d = tid & 63;
      const int* rowp = seq + (r0 + row) * 100;
      float s = 0.f; int cnt = 0;
      for (int l = 0; l < 100; ++l) {
        int id = rowp[l];
        cnt += (id != 0);
        s += emb[id * 64 + d];
      }
      p_s[row * 64 + d] = s / sqrtf((float)cnt);
    }
    __syncthreads();

    // h: 4 cells/thread
#pragma unroll
    for (int i = 0; i < 4; ++i) {
      int c = tid + i * 512;
      int row = c >> 8, j = c & 255;
      float a = b1[j];
      for (int k = 0; k < 64; ++k)
        a = fmaf(p_s[row * 64 + k], W1[k * 256 + j], a);
      h_s[row * 256 + j] = fmaxf(a, 0.f);
    }
    __syncthreads();

    // mu: 1 cell/thread
    {
      int row = tid >> 6, j = tid & 63;
      float a = b2[j];
      for (int k = 0; k < 256; ++k)
        a = fmaf(h_s[row * 256 + k], W2[k * 128 + j], a);
      mu_s[row * 64 + j] = a;
    }
    __syncthreads();

    // cp: 1 cell/thread -> global cproj
    {
      int row = tid >> 6, j = tid & 63;
      float a = bc[j];
      for (int k = 0; k < 64; ++k)
        a = fmaf(mu_s[row * 64 + k], Wc[k * 64 + j], a);
      cproj[(r0 + row) * 64 + j] = a;
    }
  } else {
    // prep for t = blockIdx - 1024 (64 of 512 threads active)
    __shared__ float temb[64];
    const int t = blockIdx.x - 1024;
    const int d = tid;
    if (d < 64) {
      const float lg = logf(10000.0f);
      int i = d & 31;
      float fr  = expf((-lg * (float)i) / 32.0f);
      float ang = (float)t * fr;
      temb[d] = (d < 32) ? cosf(ang) : sinf(ang);
      if (d == 0) {
        const float start = (float)(5.0 * 1e-4);
        const float stop  = (float)(5.0 * 0.02);
        const float delta = stop - start;
        float prod = 1.f, acp_prev = 1.f, beta = 0.f, alpha = 1.f;
        for (int i2 = 0; i2 <= t; ++i2) {
          beta  = start + ((float)i2 * delta) / 199.0f;
          alpha = 1.0f - beta;
          acp_prev = prod;
          prod = prod * alpha;
        }
        float acp = prod;
        float om  = 1.0f - acp;
        sched[t * 8 + 0] = sqrtf(1.0f / acp);
        sched[t * 8 + 1] = sqrtf(1.0f / acp - 1.0f);
        sched[t * 8 + 2] = beta * sqrtf(acp_prev) / om;
        sched[t * 8 + 3] = (1.0f - acp_prev) * sqrtf(alpha) / om;
        float pv = beta * (1.0f - acp_prev) / om;
        sched[t * 8 + 4] = (t > 0) ? sqrtf(pv) : 0.0f;
        uint32_t fk0, fk1;
        threefry2x32(0u, 2u, 0u, (uint32_t)t, fk0, fk1);
        ((uint32_t*)sched)[t * 8 + 5] = fk0;
        ((uint32_t*)sched)[t * 8 + 6] = fk1;
      }
    }
    __syncthreads();
    if (d < 64) {
      float acc = bt[d] + bin[d];
      for (int k = 0; k < 64; ++k)
        acc = fmaf(temb[k], Wt[k * 64 + d], acc);
      tpb[t * 64 + d] = acc;
    }
  }
}

// ---------------------------------------------------------------------------
// K_ddpm: 512 blocks x 512 threads (8 waves). Block owns 16 rows.
// BYTE-IDENTICAL to r24/r27 (420.9 us proven). Waves 0-3 GEMV (full-K,
// weights in regs); ALL 8 waves 2 noise draws/lane/step (bits segA, erfinv
// segB), producer cells cb = w*128 + lane*2.
#define XLDW  72   // X/H row stride (shorts); 144 B -> 16B-aligned frags
#define NBW   68   // nbuf row stride (floats)

__global__
__attribute__((amdgpu_flat_work_group_size(512, 512), amdgpu_waves_per_eu(4, 4)))
void k_ddpm(const float* __restrict__ Win, const float* __restrict__ Wout,
            const float* __restrict__ bout,
            const float* __restrict__ cproj, const float* __restrict__ tpb,
            const float* __restrict__ sched, float* __restrict__ out)
{
  __shared__ __align__(16) short Xh[16 * XLDW], Xl[16 * XLDW];
  __shared__ __align__(16) short Hh[16 * XLDW], Hl[16 * XLDW];
  __shared__ __align__(16) float nbuf[2 * 16 * NBW];
  // total: 4*2304 + 8704 = 17920 B

  const int tid  = threadIdx.x;
  const int lane = tid & 63;
  const int w    = tid >> 6;
  const bool gemv = (w < 4);
  const int r0g  = blockIdx.x * 16;
  const uint32_t* su = (const uint32_t*)sched;

  // ---- GEMV-wave ids
  const int nt   = w & 3;
  const int nn   = lane & 15;
  const int quad = lane >> 4;
  const int dim  = nt * 16 + nn;
  const int arow = nn;
  const int kq0  = quad * 8;
  const int kq1  = 32 + quad * 8;
  const int rowb = quad * 4;                       // owned rows rowb..rowb+3

  // ---- producer ids (ALL waves): 2 consecutive cells
  const int cb   = w * 128 + lane * 2;             // cell base (row*64+dim)
  const uint32_t jn = (uint32_t)(r0g * 64 + cb);   // global noise index base
  const int nrow = cb >> 6;
  const int ndim = cb & 63;
  float* nb_w = &nbuf[nrow * NBW + ndim];          // + buf*16*NBW at use

  // ---- GEMV state
  short8 wiH0, wiL0, wiH1, wiL1, woH0, woL0, woH1, woL1;
  float cp[4] = {0.f, 0.f, 0.f, 0.f}, xo[4] = {0.f, 0.f, 0.f, 0.f};
  float bo = 0.f, tp = 0.f;
  uint32_t j0 = 0;

  if (gemv) {
#pragma unroll
    for (int j = 0; j < 8; ++j) {
      short h, l;
      split_bf16(Win[(kq0 + j) * 64 + dim], h, l);  wiH0[j] = h; wiL0[j] = l;
      split_bf16(Win[(kq1 + j) * 64 + dim], h, l);  wiH1[j] = h; wiL1[j] = l;
      split_bf16(Wout[(kq0 + j) * 64 + dim], h, l); woH0[j] = h; woL0[j] = l;
      split_bf16(Wout[(kq1 + j) * 64 + dim], h, l); woH1[j] = h; woL1[j] = l;
    }
    bo = bout[dim];
    j0 = (uint32_t)((r0g + rowb) * 64 + dim);
#pragma unroll
    for (int r = 0; r < 4; ++r) cp[r] = cproj[j0 + r * 64u];
#pragma unroll
    for (int r = 0; r < 4; ++r) {
      xo[r] = jax_bits_to_normal(jax_random_bits32(0u, 1u, j0 + r * 64u));
      short h, l;
      split_bf16(xo[r], h, l);
      Xh[(rowb + r) * XLDW + dim] = h; Xl[(rowb + r) * XLDW + dim] = l;
    }
    tp = tpb[199 * 64 + dim];
  }
  // prologue noise for t=199 into nbuf[1]: ALL waves, 2 cells each
  {
    const uint32_t fk0 = su[199 * 8 + 5];
    const uint32_t fk1 = su[199 * 8 + 6];
    float* d = nb_w + 16 * NBW;                    // buf 1
    d[0] = jax_bits_to_normal(jax_random_bits32(fk0, fk1, jn + 0u));
    d[1] = jax_bits_to_normal(jax_random_bits32(fk0, fk1, jn + 1u));
  }
  __syncthreads();

#pragma unroll 1
  for (int t = 199; t >= 0; --t) {
    // draw setup for step t-1
    uint32_t gk0 = 0, gk1 = 0;
    float* nd = nullptr;
    if (t > 0) {
      gk0 = su[(t - 1) * 8 + 5];
      gk1 = su[(t - 1) * 8 + 6];
      nd = nb_w + ((t - 1) & 1) * 16 * NBW;
    }

    float sr = 0.f, srm1 = 0.f, c1 = 0.f, c2 = 0.f, sg = 0.f, tpn = 0.f;
    f32x4 acc;

    if (gemv) {
      sr   = sched[t * 8 + 0];
      srm1 = sched[t * 8 + 1];
      c1   = sched[t * 8 + 2];
      c2   = sched[t * 8 + 3];
      sg   = sched[t * 8 + 4];

      // ---- phase A: in-GEMV, full K=64, bias in all 4 owned slots
#pragma unroll
      for (int r = 0; r < 4; ++r) acc[r] = tp + cp[r];
      {
        short8 xh0 = ld_frag16(&Xh[arow * XLDW + kq0]);
        short8 xl0 = ld_frag16(&Xl[arow * XLDW + kq0]);
        short8 xh1 = ld_frag16(&Xh[arow * XLDW + kq1]);
        short8 xl1 = ld_frag16(&Xl[arow * XLDW + kq1]);
        acc = __builtin_amdgcn_mfma_f32_16x16x32_bf16(xl0, wiH0, acc, 0, 0, 0);
        acc = __builtin_amdgcn_mfma_f32_16x16x32_bf16(xh0, wiL0, acc, 0, 0, 0);
        acc = __builtin_amdgcn_mfma_f32_16x16x32_bf16(xh0, wiH0, acc, 0, 0, 0);
        acc = __builtin_amdgcn_mfma_f32_16x16x32_bf16(xl1, wiH1, acc, 0, 0, 0);
        acc = __builtin_amdgcn_mfma_f32_16x16x32_bf16(xh1, wiL1, acc, 0, 0, 0);
        acc = __builtin_amdgcn_mfma_f32_16x16x32_bf16(xh1, wiH1, acc, 0, 0, 0);
      }
#pragma unroll
      for (int r = 0; r < 4; ++r) {
        float v = acc[r];
        v = v * __builtin_amdgcn_rcpf(1.0f + __expf(-v));
        short h, l;
        split_bf16(v, h, l);
        Hh[(rowb + r) * XLDW + dim] = h; Hl[(rowb + r) * XLDW + dim] = l;
      }
      int tn = (t > 0) ? (t - 1) : 0;
      tpn = tpb[tn * 64 + dim];                    // prefetch next tp
    }
    // segA (all 8 waves): BOTH threefry chains for step t-1 (bits only)
    uint32_t b0 = 0, b1v = 0;
    if (t > 0) {
      b0  = jax_random_bits32(gk0, gk1, jn + 0u);
      b1v = jax_random_bits32(gk0, gk1, jn + 1u);
    }
    __syncthreads();                                // B1

    if (gemv) {
      // noise for this step (buf t&1 fully written by end of iter t+1)
      float n[4];
      const float* nr = &nbuf[(t & 1) * 16 * NBW + rowb * NBW + dim];
#pragma unroll
      for (int r = 0; r < 4; ++r) n[r] = nr[r * NBW];

      // ---- phase B: out-GEMV, full K=64, update 4 cells, restage X
      f32x4 eac;
#pragma unroll
      for (int r = 0; r < 4; ++r) eac[r] = bo;
      {
        short8 hh0 = ld_frag16(&Hh[arow * XLDW + kq0]);
        short8 hl0 = ld_frag16(&Hl[arow * XLDW + kq0]);
        short8 hh1 = ld_frag16(&Hh[arow * XLDW + kq1]);
        short8 hl1 = ld_frag16(&Hl[arow * XLDW + kq1]);
        eac = __builtin_amdgcn_mfma_f32_16x16x32_bf16(hl0, woH0, eac, 0, 0, 0);
        eac = __builtin_amdgcn_mfma_f32_16x16x32_bf16(hh0, woL0, eac, 0, 0, 0);
        eac = __builtin_amdgcn_mfma_f32_16x16x32_bf16(hh0, woH0, eac, 0, 0, 0);
        eac = __builtin_amdgcn_mfma_f32_16x16x32_bf16(hl1, woH1, eac, 0, 0, 0);
        eac = __builtin_amdgcn_mfma_f32_16x16x32_bf16(hh1, woL1, eac, 0, 0, 0);
        eac = __builtin_amdgcn_mfma_f32_16x16x32_bf16(hh1, woH1, eac, 0, 0, 0);
      }
#pragma unroll
      for (int r = 0; r < 4; ++r) {
        float xc = fminf(1.f, fmaxf(-1.f, sr * xo[r] - srm1 * eac[r]));
        xo[r] = c1 * xc + c2 * xo[r] + sg * n[r];
        short h, l;
        split_bf16(xo[r], h, l);
        Xh[(rowb + r) * XLDW + dim] = h; Xl[(rowb + r) * XLDW + dim] = l;
      }
      tp = tpn;
    }
    // segB (all 8 waves): BOTH erfinv chains + nbuf write
    if (t > 0) {
      nd[0] = jax_bits_to_normal(b0);
      nd[1] = jax_bits_to_normal(b1v);
    }
    __syncthreads();                                // B2
  }

  if (gemv) {
#pragma unroll
    for (int r = 0; r < 4; ++r) out[j0 + r * 64u] = xo[r];
  }
}

// ---------------------------------------------------------------------------
extern "C" void kernel_launch(void* const* d_in, const int* in_sizes, int n_in,
                              void* d_out, int out_size, void* d_ws, size_t ws_size,
                              hipStream_t stream)
{
  const int*   seq  = (const int*)  d_in[0];
  const float* emb  = (const float*)d_in[1];
  const float* W1   = (const float*)d_in[2];
  const float* b1   = (const float*)d_in[3];
  const float* W2   = (const float*)d_in[4];
  const float* b2   = (const float*)d_in[5];
  const float* Win  = (const float*)d_in[6];
  const float* bin  = (const float*)d_in[7];
  const float* Wt   = (const float*)d_in[8];
  const float* bt   = (const float*)d_in[9];
  const float* Wc   = (const float*)d_in[10];
  const float* bc   = (const float*)d_in[11];
  const float* Wout = (const float*)d_in[12];
  const float* bout = (const float*)d_in[13];

  float* out   = (float*)d_out;
  float* ws    = (float*)d_ws;
  float* cproj = ws;                       // 524288 floats
  float* tpb   = ws + 524288;              // 12800 floats
  float* sched = ws + 524288 + 12800;      // 1600 floats (t*8 layout)

  k_poolenc<<<1224, 512, 0, stream>>>(seq, emb, W1, b1, W2, b2, Wc, bc,
                                      cproj, Wt, bt, bin, tpb, sched);
  k_ddpm <<<512, 512, 0, stream>>>(Win, Wout, bout, cproj, tpb, sched, out);
}

// Round 17
// 526.248 us; speedup vs baseline: 1.4429x; 1.0230x over previous
//
#include <hip/hip_runtime.h>
#include <cstdint>

// ---------------------------------------------------------------------------
// DDPM + VAE query encoder, MI355X round 29 == r24 REVERT (best measured:
// 523.7 us total, k_ddpm 425.4). r28 post-mortem: pool->enc fusion 0-for-3
// (560/547/538 vs 523.7) -- the prologue's latency-bound gather packs best
// in r24's split arrangement. t-loop stable at 421-428 across 6 rounds;
// seven structural attacks exhausted (occupancy x3 lost to spills/dup,
// chain-ILP neutral, balance/full-K/weight-hoist won). Locking in r24.
// ---------------------------------------------------------------------------

#define DEVI __device__ __forceinline__

typedef __attribute__((ext_vector_type(8))) short short8;
typedef __attribute__((ext_vector_type(4))) float f32x4;

DEVI void threefry2x32(uint32_t k0, uint32_t k1, uint32_t x0, uint32_t x1,
                       uint32_t &o0, uint32_t &o1)
{
  const uint32_t ks2 = k0 ^ k1 ^ 0x1BD11BDAu;
  x0 += k0; x1 += k1;
#define TFR(r) { x0 += x1; x1 = __builtin_rotateleft32(x1, r); x1 ^= x0; }
  TFR(13u) TFR(15u) TFR(26u) TFR(6u)   x0 += k1;  x1 += ks2 + 1u;
  TFR(17u) TFR(29u) TFR(16u) TFR(24u)  x0 += ks2; x1 += k0 + 2u;
  TFR(13u) TFR(15u) TFR(26u) TFR(6u)   x0 += k0;  x1 += k1 + 3u;
  TFR(17u) TFR(29u) TFR(16u) TFR(24u)  x0 += k1;  x1 += ks2 + 4u;
  TFR(13u) TFR(15u) TFR(26u) TFR(6u)   x0 += ks2; x1 += k0 + 5u;
#undef TFR
  o0 = x0; o1 = x1;
}

DEVI uint32_t jax_random_bits32(uint32_t k0, uint32_t k1, uint32_t j)
{
  uint32_t a, b;
  threefry2x32(k0, k1, 0u, j, a, b);
  return a ^ b;
}

DEVI float jax_bits_to_normal(uint32_t bits)
{
  const float LO = -0.99999994f;
  float f = __uint_as_float((bits >> 9) | 0x3f800000u) - 1.0f;
  float u = fmaxf(LO, f * 2.0f + LO);
  float w = -__logf((1.0f - u) * (1.0f + u));
  float p;
  if (w < 5.0f) {
    w = w - 2.5f;
    p =              2.81022636e-08f;
    p = fmaf(p, w,   3.43273939e-07f);
    p = fmaf(p, w,  -3.5233877e-06f);
    p = fmaf(p, w,  -4.39150654e-06f);
    p = fmaf(p, w,   0.00021858087f);
    p = fmaf(p, w,  -0.00125372503f);
    p = fmaf(p, w,  -0.00417768164f);
    p = fmaf(p, w,   0.246640727f);
    p = fmaf(p, w,   1.50140941f);
  } else {
    w = sqrtf(w) - 3.0f;
    p =             -0.000200214257f;
    p = fmaf(p, w,   0.000100950558f);
    p = fmaf(p, w,   0.00134934322f);
    p = fmaf(p, w,  -0.00367342844f);
    p = fmaf(p, w,   0.00573950773f);
    p = fmaf(p, w,  -0.0076224613f);
    p = fmaf(p, w,   0.00943887047f);
    p = fmaf(p, w,   1.00167406f);
    p = fmaf(p, w,   2.83297682f);
  }
  return 1.41421356237f * (p * u);
}

DEVI short bf16_hi_trunc(float x) { return (short)(__float_as_uint(x) >> 16); }
DEVI float bf16_to_f32(short h)
{
  return __uint_as_float(((uint32_t)(unsigned short)h) << 16);
}
DEVI void split_bf16(float x, short &h, short &l)
{
  h = bf16_hi_trunc(x);
  float r = x - bf16_to_f32(h);
  l = bf16_hi_trunc(r);
}

// 8-short fragment from 16B-aligned LDS (stride-72 rows): one b128 read.
DEVI short8 ld_frag16(const short* p)
{
  union { int4 v; short8 s; } u;
  u.v = *(const int4*)p;
  return u.s;
}

// ---------------------------------------------------------------------------
// k_poolprep: blocks [0,2048) = pool (4 rows each); blocks [2048,2248) =
// prep for t = blockIdx-2048. Independent inputs; prep hides under pool.
__global__ __launch_bounds__(256)
void k_poolprep(const int* __restrict__ seq, const float* __restrict__ emb,
                float* __restrict__ pooled,
                const float* __restrict__ Wt, const float* __restrict__ bt,
                const float* __restrict__ bin, float* __restrict__ tpb,
                float* __restrict__ sched)
{
  if (blockIdx.x < 2048u) {
    const int lane = threadIdx.x & 63;
    const int r    = blockIdx.x * 4 + (threadIdx.x >> 6);
    const int* row = seq + r * 100;
    float s = 0.f;
    int cnt = 0;
    for (int l = 0; l < 100; ++l) {
      int id = row[l];
      cnt += (id != 0);
      s += emb[id * 64 + lane];
    }
    pooled[r * 64 + lane] = s / sqrtf((float)cnt);
  } else {
    __shared__ float temb[64];
    const int t = blockIdx.x - 2048;
    const int d = threadIdx.x;
    if (d < 64) {
      const float lg = logf(10000.0f);
      int i = d & 31;
      float fr  = expf((-lg * (float)i) / 32.0f);
      float ang = (float)t * fr;
      temb[d] = (d < 32) ? cosf(ang) : sinf(ang);
      if (d == 0) {
        const float start = (float)(5.0 * 1e-4);
        const float stop  = (float)(5.0 * 0.02);
        const float delta = stop - start;
        float prod = 1.f, acp_prev = 1.f, beta = 0.f, alpha = 1.f;
        for (int i2 = 0; i2 <= t; ++i2) {
          beta  = start + ((float)i2 * delta) / 199.0f;
          alpha = 1.0f - beta;
          acp_prev = prod;
          prod = prod * alpha;
        }
        float acp = prod;
        float om  = 1.0f - acp;
        sched[t * 8 + 0] = sqrtf(1.0f / acp);
        sched[t * 8 + 1] = sqrtf(1.0f / acp - 1.0f);
        sched[t * 8 + 2] = beta * sqrtf(acp_prev) / om;
        sched[t * 8 + 3] = (1.0f - acp_prev) * sqrtf(alpha) / om;
        float pv = beta * (1.0f - acp_prev) / om;
        sched[t * 8 + 4] = (t > 0) ? sqrtf(pv) : 0.0f;
        uint32_t fk0, fk1;
        threefry2x32(0u, 2u, 0u, (uint32_t)t, fk0, fk1);
        ((uint32_t*)sched)[t * 8 + 5] = fk0;
        ((uint32_t*)sched)[t * 8 + 6] = fk1;
      }
    }
    __syncthreads();
    if (d < 64) {
      float acc = bt[d] + bin[d];
      for (int k = 0; k < 64; ++k)
        acc = fmaf(temb[k], Wt[k * 64 + d], acc);
      tpb[t * 64 + d] = acc;
    }
  }
}

// ---------------------------------------------------------------------------
__global__ __launch_bounds__(256)
void k_enc(const float* __restrict__ pooled,
           const float* __restrict__ W1, const float* __restrict__ b1,
           const float* __restrict__ W2, const float* __restrict__ b2,
           const float* __restrict__ Wc, const float* __restrict__ bc,
           float* __restrict__ cproj)
{
  __shared__ float p_s[8][64];
  __shared__ float h_s[8][256];
  __shared__ float mu_s[8][64];
  const int tid = threadIdx.x;
  const int r0  = blockIdx.x * 8;

  for (int i = tid; i < 8 * 64; i += 256)
    p_s[i >> 6][i & 63] = pooled[r0 * 64 + i];
  __syncthreads();

  float hacc[8];
#pragma unroll
  for (int r = 0; r < 8; ++r) hacc[r] = b1[tid];
  for (int k = 0; k < 64; ++k) {
    float w = W1[k * 256 + tid];
#pragma unroll
    for (int r = 0; r < 8; ++r) hacc[r] = fmaf(p_s[r][k], w, hacc[r]);
  }
#pragma unroll
  for (int r = 0; r < 8; ++r) h_s[r][tid] = fmaxf(hacc[r], 0.f);
  __syncthreads();

#pragma unroll
  for (int pass = 0; pass < 2; ++pass) {
    int r = pass * 4 + (tid >> 6);
    int j = tid & 63;
    float acc = b2[j];
    for (int k = 0; k < 256; ++k)
      acc = fmaf(h_s[r][k], W2[k * 128 + j], acc);
    mu_s[r][j] = acc;
  }
  __syncthreads();

#pragma unroll
  for (int pass = 0; pass < 2; ++pass) {
    int r = pass * 4 + (tid >> 6);
    int j = tid & 63;
    float acc = bc[j];
    for (int k = 0; k < 64; ++k)
      acc = fmaf(mu_s[r][k], Wc[k * 64 + j], acc);
    cproj[(r0 + r) * 64 + j] = acc;
  }
}

// ---------------------------------------------------------------------------
// K_ddpm: 512 blocks x 512 threads (8 waves). Block owns 16 rows.
// Waves 0-3 (GEMV): wave nt owns cols 16nt..16nt+15; lane (quad,nn) owns
//   rows quad*4..+3 at col dim. Full-K GEMV, 6 MFMA/phase, weights in regs.
// ALL 8 waves produce 2 noise values/lane/step, PIPELINED: segA = both
//   threefry chains (bits, ILP-2), segB = both erfinv chains + nbuf write.
//   Producer cells cb = w*128 + lane*2 (bijective over 1024 block cells).
#define XLDW  72   // X/H row stride (shorts); 144 B -> 16B-aligned frags
#define NBW   68   // nbuf row stride (floats)

__global__
__attribute__((amdgpu_flat_work_group_size(512, 512), amdgpu_waves_per_eu(4, 4)))
void k_ddpm(const float* __restrict__ Win, const float* __restrict__ Wout,
            const float* __restrict__ bout,
            const float* __restrict__ cproj, const float* __restrict__ tpb,
            const float* __restrict__ sched, float* __restrict__ out)
{
  __shared__ __align__(16) short Xh[16 * XLDW], Xl[16 * XLDW];
  __shared__ __align__(16) short Hh[16 * XLDW], Hl[16 * XLDW];
  __shared__ __align__(16) float nbuf[2 * 16 * NBW];
  // total: 4*2304 + 8704 = 17920 B

  const int tid  = threadIdx.x;
  const int lane = tid & 63;
  const int w    = tid >> 6;
  const bool gemv = (w < 4);
  const int r0g  = blockIdx.x * 16;
  const uint32_t* su = (const uint32_t*)sched;

  // ---- GEMV-wave ids
  const int nt   = w & 3;
  const int nn   = lane & 15;
  const int quad = lane >> 4;
  const int dim  = nt * 16 + nn;
  const int arow = nn;
  const int kq0  = quad * 8;
  const int kq1  = 32 + quad * 8;
  const int rowb = quad * 4;                       // owned rows rowb..rowb+3

  // ---- producer ids (ALL waves): 2 consecutive cells
  const int cb   = w * 128 + lane * 2;             // cell base (row*64+dim)
  const uint32_t jn = (uint32_t)(r0g * 64 + cb);   // global noise index base
  const int nrow = cb >> 6;
  const int ndim = cb & 63;
  float* nb_w = &nbuf[nrow * NBW + ndim];          // + buf*16*NBW at use

  // ---- GEMV state
  short8 wiH0, wiL0, wiH1, wiL1, woH0, woL0, woH1, woL1;
  float cp[4] = {0.f, 0.f, 0.f, 0.f}, xo[4] = {0.f, 0.f, 0.f, 0.f};
  float bo = 0.f, tp = 0.f;
  uint32_t j0 = 0;

  if (gemv) {
#pragma unroll
    for (int j = 0; j < 8; ++j) {
      short h, l;
      split_bf16(Win[(kq0 + j) * 64 + dim], h, l);  wiH0[j] = h; wiL0[j] = l;
      split_bf16(Win[(kq1 + j) * 64 + dim], h, l);  wiH1[j] = h; wiL1[j] = l;
      split_bf16(Wout[(kq0 + j) * 64 + dim], h, l); woH0[j] = h; woL0[j] = l;
      split_bf16(Wout[(kq1 + j) * 64 + dim], h, l); woH1[j] = h; woL1[j] = l;
    }
    bo = bout[dim];
    j0 = (uint32_t)((r0g + rowb) * 64 + dim);
#pragma unroll
    for (int r = 0; r < 4; ++r) cp[r] = cproj[j0 + r * 64u];
#pragma unroll
    for (int r = 0; r < 4; ++r) {
      xo[r] = jax_bits_to_normal(jax_random_bits32(0u, 1u, j0 + r * 64u));
      short h, l;
      split_bf16(xo[r], h, l);
      Xh[(rowb + r) * XLDW + dim] = h; Xl[(rowb + r) * XLDW + dim] = l;
    }
    tp = tpb[199 * 64 + dim];
  }
  // prologue noise for t=199 into nbuf[1]: ALL waves, 2 cells each
  {
    const uint32_t fk0 = su[199 * 8 + 5];
    const uint32_t fk1 = su[199 * 8 + 6];
    float* d = nb_w + 16 * NBW;                    // buf 1
    d[0] = jax_bits_to_normal(jax_random_bits32(fk0, fk1, jn + 0u));
    d[1] = jax_bits_to_normal(jax_random_bits32(fk0, fk1, jn + 1u));
  }
  __syncthreads();

#pragma unroll 1
  for (int t = 199; t >= 0; --t) {
    // draw setup for step t-1
    uint32_t gk0 = 0, gk1 = 0;
    float* nd = nullptr;
    if (t > 0) {
      gk0 = su[(t - 1) * 8 + 5];
      gk1 = su[(t - 1) * 8 + 6];
      nd = nb_w + ((t - 1) & 1) * 16 * NBW;
    }

    float sr = 0.f, srm1 = 0.f, c1 = 0.f, c2 = 0.f, sg = 0.f, tpn = 0.f;
    f32x4 acc;

    if (gemv) {
      sr   = sched[t * 8 + 0];
      srm1 = sched[t * 8 + 1];
      c1   = sched[t * 8 + 2];
      c2   = sched[t * 8 + 3];
      sg   = sched[t * 8 + 4];

      // ---- phase A: in-GEMV, full K=64, bias in all 4 owned slots
#pragma unroll
      for (int r = 0; r < 4; ++r) acc[r] = tp + cp[r];
      {
        short8 xh0 = ld_frag16(&Xh[arow * XLDW + kq0]);
        short8 xl0 = ld_frag16(&Xl[arow * XLDW + kq0]);
        short8 xh1 = ld_frag16(&Xh[arow * XLDW + kq1]);
        short8 xl1 = ld_frag16(&Xl[arow * XLDW + kq1]);
        acc = __builtin_amdgcn_mfma_f32_16x16x32_bf16(xl0, wiH0, acc, 0, 0, 0);
        acc = __builtin_amdgcn_mfma_f32_16x16x32_bf16(xh0, wiL0, acc, 0, 0, 0);
        acc = __builtin_amdgcn_mfma_f32_16x16x32_bf16(xh0, wiH0, acc, 0, 0, 0);
        acc = __builtin_amdgcn_mfma_f32_16x16x32_bf16(xl1, wiH1, acc, 0, 0, 0);
        acc = __builtin_amdgcn_mfma_f32_16x16x32_bf16(xh1, wiL1, acc, 0, 0, 0);
        acc = __builtin_amdgcn_mfma_f32_16x16x32_bf16(xh1, wiH1, acc, 0, 0, 0);
      }
#pragma unroll
      for (int r = 0; r < 4; ++r) {
        float v = acc[r];
        v = v * __builtin_amdgcn_rcpf(1.0f + __expf(-v));
        short h, l;
        split_bf16(v, h, l);
        Hh[(rowb + r) * XLDW + dim] = h; Hl[(rowb + r) * XLDW + dim] = l;
      }
      int tn = (t > 0) ? (t - 1) : 0;
      tpn = tpb[tn * 64 + dim];                    // prefetch next tp
    }
    // segA (all 8 waves): BOTH threefry chains for step t-1 (bits only)
    uint32_t b0 = 0, b1v = 0;
    if (t > 0) {
      b0  = jax_random_bits32(gk0, gk1, jn + 0u);
      b1v = jax_random_bits32(gk0, gk1, jn + 1u);
    }
    __syncthreads();                                // B1

    if (gemv) {
      // noise for this step (buf t&1 fully written by end of iter t+1)
      float n[4];
      const float* nr = &nbuf[(t & 1) * 16 * NBW + rowb * NBW + dim];
#pragma unroll
      for (int r = 0; r < 4; ++r) n[r] = nr[r * NBW];

      // ---- phase B: out-GEMV, full K=64, update 4 cells, restage X
      f32x4 eac;
#pragma unroll
      for (int r = 0; r < 4; ++r) eac[r] = bo;
      {
        short8 hh0 = ld_frag16(&Hh[arow * XLDW + kq0]);
        short8 hl0 = ld_frag16(&Hl[arow * XLDW + kq0]);
        short8 hh1 = ld_frag16(&Hh[arow * XLDW + kq1]);
        short8 hl1 = ld_frag16(&Hl[arow * XLDW + kq1]);
        eac = __builtin_amdgcn_mfma_f32_16x16x32_bf16(hl0, woH0, eac, 0, 0, 0);
        eac = __builtin_amdgcn_mfma_f32_16x16x32_bf16(hh0, woL0, eac, 0, 0, 0);
        eac = __builtin_amdgcn_mfma_f32_16x16x32_bf16(hh0, woH0, eac, 0, 0, 0);
        eac = __builtin_amdgcn_mfma_f32_16x16x32_bf16(hl1, woH1, eac, 0, 0, 0);
        eac = __builtin_amdgcn_mfma_f32_16x16x32_bf16(hh1, woL1, eac, 0, 0, 0);
        eac = __builtin_amdgcn_mfma_f32_16x16x32_bf16(hh1, woH1, eac, 0, 0, 0);
      }
#pragma unroll
      for (int r = 0; r < 4; ++r) {
        float xc = fminf(1.f, fmaxf(-1.f, sr * xo[r] - srm1 * eac[r]));
        xo[r] = c1 * xc + c2 * xo[r] + sg * n[r];
        short h, l;
        split_bf16(xo[r], h, l);
        Xh[(rowb + r) * XLDW + dim] = h; Xl[(rowb + r) * XLDW + dim] = l;
      }
      tp = tpn;
    }
    // segB (all 8 waves): BOTH erfinv chains + nbuf write
    if (t > 0) {
      nd[0] = jax_bits_to_normal(b0);
      nd[1] = jax_bits_to_normal(b1v);
    }
    __syncthreads();                                // B2
  }

  if (gemv) {
#pragma unroll
    for (int r = 0; r < 4; ++r) out[j0 + r * 64u] = xo[r];
  }
}

// ---------------------------------------------------------------------------
extern "C" void kernel_launch(void* const* d_in, const int* in_sizes, int n_in,
                              void* d_out, int out_size, void* d_ws, size_t ws_size,
                              hipStream_t stream)
{
  const int*   seq  = (const int*)  d_in[0];
  const float* emb  = (const float*)d_in[1];
  const float* W1   = (const float*)d_in[2];
  const float* b1   = (const float*)d_in[3];
  const float* W2   = (const float*)d_in[4];
  const float* b2   = (const float*)d_in[5];
  const float* Win  = (const float*)d_in[6];
  const float* bin  = (const float*)d_in[7];
  const float* Wt   = (const float*)d_in[8];
  const float* bt   = (const float*)d_in[9];
  const float* Wc   = (const float*)d_in[10];
  const float* bc   = (const float*)d_in[11];
  const float* Wout = (const float*)d_in[12];
  const float* bout = (const float*)d_in[13];

  float* out   = (float*)d_out;
  float* ws    = (float*)d_ws;
  float* cproj = ws;                       // 524288 floats
  float* tpb   = ws + 524288;              // 12800 floats
  float* sched = ws + 524288 + 12800;      // 1600 floats (t*8 layout)
  float* pooled = out;                     // reuse d_out as scratch

  k_poolprep<<<2248, 256, 0, stream>>>(seq, emb, pooled, Wt, bt, bin, tpb, sched);
  k_enc  <<<1024, 256, 0, stream>>>(pooled, W1, b1, W2, b2, Wc, bc, cproj);
  k_ddpm <<<512, 512, 0, stream>>>(Win, Wout, bout, cproj, tpb, sched, out);
}